// Round 1
// baseline (1526.547 us; speedup 1.0000x reference)
//
#include <hip/hip_runtime.h>
#include <hip/hip_bf16.h>
#include <stdint.h>

#define BB 32
#define S_SRC 128
#define S_TGT 64
#define H 300
#define VV 32000
#define M_ROWS (BB * S_TGT)   // 2048
#define KP 320                // K padded to multiple of 32

typedef __attribute__((ext_vector_type(8))) __bf16 bf16x8;
typedef __attribute__((ext_vector_type(4))) float f32x4;

__device__ inline unsigned short f2bf(float f) {
    union { float f; unsigned u; } v; v.f = f;
    unsigned r = (v.u + 0x7FFF + ((v.u >> 16) & 1)) >> 16;  // RNE
    return (unsigned short)r;
}

// ---------------- transpose the four HxH weight matrices -> ws ----------------
__global__ void transpose4(const float* W0, const float* W1, const float* W2,
                           const float* W3, float* dst) {
    const float* srcs[4] = {W0, W1, W2, W3};
    const float* src = srcs[blockIdx.z];
    float* d = dst + (size_t)blockIdx.z * (H * H);
    __shared__ float tile[32][33];
    int j0 = blockIdx.y * 32, k0 = blockIdx.x * 32;
    for (int r = threadIdx.y; r < 32; r += blockDim.y) {
        int j = j0 + r, k = k0 + threadIdx.x;
        tile[r][threadIdx.x] = (j < H && k < H) ? src[(size_t)j * H + k] : 0.f;
    }
    __syncthreads();
    for (int r = threadIdx.y; r < 32; r += blockDim.y) {
        int k = k0 + r, j = j0 + threadIdx.x;
        if (k < H && j < H) d[(size_t)k * H + j] = tile[threadIdx.x][r];
    }
}

// ---------------- P[m][j] = EN[x[m]] @ WihT + bih + bhh  (m = b*128+t) --------
#define RPB 8
__global__ __launch_bounds__(192) void pproj(const int* __restrict__ x,
                                             const float* __restrict__ EN,
                                             const float* __restrict__ WihT,
                                             const float* __restrict__ bih,
                                             const float* __restrict__ bhh,
                                             float* __restrict__ P) {
    __shared__ float xe[RPB][H];
    int m0 = blockIdx.x * RPB;
    int tid = threadIdx.x;
    for (int r = 0; r < RPB; ++r) {
        int idx = x[m0 + r];
        for (int c = tid; c < H; c += 192) xe[r][c] = EN[(size_t)idx * H + c];
    }
    __syncthreads();
    if (tid < 150) {
        int j = tid * 2;
        float a0[RPB], a1[RPB];
#pragma unroll
        for (int r = 0; r < RPB; ++r) { a0[r] = 0.f; a1[r] = 0.f; }
        const float* wp = WihT + j;
        for (int k = 0; k < H; ++k) {
            float2 w = *reinterpret_cast<const float2*>(wp + (size_t)k * H);
#pragma unroll
            for (int r = 0; r < RPB; ++r) {
                float xv = xe[r][k];
                a0[r] += xv * w.x; a1[r] += xv * w.y;
            }
        }
        float b0 = bih[j] + bhh[j], b1 = bih[j + 1] + bhh[j + 1];
#pragma unroll
        for (int r = 0; r < RPB; ++r) {
            P[(size_t)(m0 + r) * H + j]     = a0[r] + b0;
            P[(size_t)(m0 + r) * H + j + 1] = a1[r] + b1;
        }
    }
}

// ---------------- encoder recurrence: h = tanh(P[t] + h @ WhhT) --------------
__global__ __launch_bounds__(192) void encoder(const float* __restrict__ h0,
                                               const float* __restrict__ P,
                                               const float* __restrict__ WhhT,
                                               float* __restrict__ c) {
    __shared__ float h[H];
    int b = blockIdx.x, tid = threadIdx.x;
    for (int i = tid; i < H; i += 192) h[i] = h0[(size_t)b * H + i];
    __syncthreads();
    int j = tid * 2;
    for (int t = 0; t < S_SRC; ++t) {
        float nh0 = 0.f, nh1 = 0.f;
        if (tid < 150) {
            float a0 = P[(size_t)(b * S_SRC + t) * H + j];
            float a1 = P[(size_t)(b * S_SRC + t) * H + j + 1];
            const float* wp = WhhT + j;
#pragma unroll 4
            for (int k = 0; k < H; ++k) {
                float2 w = *reinterpret_cast<const float2*>(wp + (size_t)k * H);
                float hv = h[k];
                a0 += hv * w.x; a1 += hv * w.y;
            }
            nh0 = tanhf(a0); nh1 = tanhf(a1);
        }
        __syncthreads();
        if (tid < 150) { h[j] = nh0; h[j + 1] = nh1; }
        __syncthreads();
    }
    for (int i = tid; i < H; i += 192) c[(size_t)b * H + i] = h[i];
}

// ---------------- s2[b][j] = c[b] @ WhhT_d + bhh_d + bih_d -------------------
__global__ __launch_bounds__(192) void sdec(const float* __restrict__ c,
                                            const float* __restrict__ WhhT_d,
                                            const float* __restrict__ bih_d,
                                            const float* __restrict__ bhh_d,
                                            float* __restrict__ s2) {
    __shared__ float cl[H];
    int b = blockIdx.x, tid = threadIdx.x;
    for (int k = tid; k < H; k += 192) cl[k] = c[(size_t)b * H + k];
    __syncthreads();
    if (tid < 150) {
        int j = tid * 2;
        float a0 = 0.f, a1 = 0.f;
        const float* wp = WhhT_d + j;
        for (int k = 0; k < H; ++k) {
            float2 w = *reinterpret_cast<const float2*>(wp + (size_t)k * H);
            a0 += cl[k] * w.x; a1 += cl[k] * w.y;
        }
        s2[(size_t)b * H + j]     = a0 + bih_d[j] + bhh_d[j];
        s2[(size_t)b * H + j + 1] = a1 + bih_d[j + 1] + bhh_d[j + 1];
    }
}

// ---------------- h_dec (bf16, K padded to 320): rows m = b*64+t -------------
__global__ __launch_bounds__(192) void hdec_k(const int* __restrict__ y,
                                              const float* __restrict__ ZH,
                                              const float* __restrict__ WihT_d,
                                              const float* __restrict__ s2,
                                              unsigned short* __restrict__ hdec) {
    __shared__ float ye[RPB][H];
    int m0 = blockIdx.x * RPB;
    int tid = threadIdx.x;
    for (int r = 0; r < RPB; ++r) {
        int idx = y[m0 + r];
        for (int c = tid; c < H; c += 192) ye[r][c] = ZH[(size_t)idx * H + c];
    }
    __syncthreads();
    if (tid < 150) {
        int j = tid * 2;
        float a0[RPB], a1[RPB];
#pragma unroll
        for (int r = 0; r < RPB; ++r) { a0[r] = 0.f; a1[r] = 0.f; }
        const float* wp = WihT_d + j;
        for (int k = 0; k < H; ++k) {
            float2 w = *reinterpret_cast<const float2*>(wp + (size_t)k * H);
#pragma unroll
            for (int r = 0; r < RPB; ++r) {
                float xv = ye[r][k];
                a0[r] += xv * w.x; a1[r] += xv * w.y;
            }
        }
#pragma unroll
        for (int r = 0; r < RPB; ++r) {
            int m = m0 + r;
            int b = m >> 6;
            float sv0 = s2[(size_t)b * H + j], sv1 = s2[(size_t)b * H + j + 1];
            hdec[(size_t)m * KP + j]     = f2bf(tanhf(a0[r] + sv0));
            hdec[(size_t)m * KP + j + 1] = f2bf(tanhf(a1[r] + sv1));
        }
    } else if (tid < 160) {
        int j = 300 + (tid - 150) * 2;   // zero the K padding 300..319
#pragma unroll
        for (int r = 0; r < RPB; ++r) {
            hdec[(size_t)(m0 + r) * KP + j]     = 0;
            hdec[(size_t)(m0 + r) * KP + j + 1] = 0;
        }
    }
}

// ---------------- out[2048,32000] = hdec @ W_out^T + b_out (bf16 MFMA) -------
#define BM 128
#define BN 128
#define BK 32
#define LDSW 40  // ushort row stride (80 B) -> breaks 64B-stride bank conflicts

__global__ __launch_bounds__(256) void gemm_out(const unsigned short* __restrict__ A,
                                                const float* __restrict__ W,
                                                const float* __restrict__ bout,
                                                float* __restrict__ out) {
    __shared__ __align__(16) unsigned short Alds[BM * LDSW];
    __shared__ __align__(16) unsigned short Blds[BN * LDSW];
    int tid = threadIdx.x;
    int lane = tid & 63, wv = tid >> 6;
    int wm = wv >> 1, wn = wv & 1;           // 2x2 waves, 64x64 each
    int m0 = blockIdx.y * BM, n0 = blockIdx.x * BN;

    f32x4 acc[4][4];
    f32x4 zero = {0.f, 0.f, 0.f, 0.f};
#pragma unroll
    for (int i = 0; i < 4; ++i)
#pragma unroll
        for (int jj = 0; jj < 4; ++jj) acc[i][jj] = zero;

    for (int k0 = 0; k0 < KP; k0 += BK) {
        // stage A tile [128][32] bf16 (already padded with zeros to K=320)
#pragma unroll
        for (int s = 0; s < 2; ++s) {
            int slot = tid + s * 256;
            int row = slot >> 2, c16 = slot & 3;
            uint4 v = *reinterpret_cast<const uint4*>(
                &A[(size_t)(m0 + row) * KP + k0 + c16 * 8]);
            *reinterpret_cast<uint4*>(&Alds[row * LDSW + c16 * 8]) = v;
        }
        // stage B tile [128][32]: rows of W_out (f32), convert to bf16, pad K>=300
#pragma unroll
        for (int s = 0; s < 2; ++s) {
            int slot = tid + s * 256;
            int row = slot >> 2, c8 = slot & 3;
            int k = k0 + c8 * 8;
            __align__(16) unsigned short tmp[8];
            if (k + 7 < H) {
                const float* src = &W[(size_t)(n0 + row) * H + k];
                float4 f0 = *reinterpret_cast<const float4*>(src);
                float4 f1 = *reinterpret_cast<const float4*>(src + 4);
                tmp[0] = f2bf(f0.x); tmp[1] = f2bf(f0.y);
                tmp[2] = f2bf(f0.z); tmp[3] = f2bf(f0.w);
                tmp[4] = f2bf(f1.x); tmp[5] = f2bf(f1.y);
                tmp[6] = f2bf(f1.z); tmp[7] = f2bf(f1.w);
            } else {
#pragma unroll
                for (int jv = 0; jv < 8; ++jv) {
                    int kk = k + jv;
                    tmp[jv] = (kk < H) ? f2bf(W[(size_t)(n0 + row) * H + kk])
                                       : (unsigned short)0;
                }
            }
            *reinterpret_cast<uint4*>(&Blds[row * LDSW + c8 * 8]) =
                *reinterpret_cast<const uint4*>(tmp);
        }
        __syncthreads();

        bf16x8 af[4], bfm[4];
#pragma unroll
        for (int i = 0; i < 4; ++i) {
            int row = wm * 64 + i * 16 + (lane & 15);
            af[i] = *reinterpret_cast<const bf16x8*>(&Alds[row * LDSW + (lane >> 4) * 8]);
        }
#pragma unroll
        for (int i = 0; i < 4; ++i) {
            int row = wn * 64 + i * 16 + (lane & 15);
            bfm[i] = *reinterpret_cast<const bf16x8*>(&Blds[row * LDSW + (lane >> 4) * 8]);
        }
#pragma unroll
        for (int i = 0; i < 4; ++i)
#pragma unroll
            for (int jj = 0; jj < 4; ++jj)
                acc[i][jj] = __builtin_amdgcn_mfma_f32_16x16x32_bf16(
                    af[i], bfm[jj], acc[i][jj], 0, 0, 0);
        __syncthreads();
    }

    // epilogue: D row=(lane>>4)*4+r, col=lane&15
#pragma unroll
    for (int jj = 0; jj < 4; ++jj) {
        int col = n0 + wn * 64 + jj * 16 + (lane & 15);
        float bo = bout[col];
#pragma unroll
        for (int i = 0; i < 4; ++i) {
            int rb = m0 + wm * 64 + i * 16 + (lane >> 4) * 4;
            f32x4 v = acc[i][jj];
#pragma unroll
            for (int r = 0; r < 4; ++r)
                out[(size_t)(rb + r) * VV + col] = v[r] + bo;
        }
    }
}

// ---------------- host ----------------
extern "C" void kernel_launch(void* const* d_in, const int* in_sizes, int n_in,
                              void* d_out, int out_size, void* d_ws, size_t ws_size,
                              hipStream_t stream) {
    const int*   x       = (const int*)d_in[0];
    const int*   y       = (const int*)d_in[1];
    const float* h0      = (const float*)d_in[2];
    const float* EN      = (const float*)d_in[3];
    const float* ZH      = (const float*)d_in[4];
    const float* enc_Wih = (const float*)d_in[5];
    const float* enc_Whh = (const float*)d_in[6];
    const float* enc_bih = (const float*)d_in[7];
    const float* enc_bhh = (const float*)d_in[8];
    const float* dec_Wih = (const float*)d_in[9];
    const float* dec_Whh = (const float*)d_in[10];
    const float* dec_bih = (const float*)d_in[11];
    const float* dec_bhh = (const float*)d_in[12];
    const float* W_out   = (const float*)d_in[13];
    const float* b_out   = (const float*)d_in[14];
    float* out = (float*)d_out;
    float* ws  = (float*)d_ws;

    // ws layout (f32 offsets):
    //   0        : WihT_enc (90000)
    //   90000    : WhhT_enc
    //   180000   : WihT_dec
    //   270000   : WhhT_dec
    //   360000   : P [4096*300]
    //   1588800  : c [32*300]
    //   1598400  : s2 [32*300]
    //   1608000  : hdec bf16 [2048*320] (ushort)
    const size_t need = 1608000ull * 4 + (size_t)M_ROWS * KP * 2;
    if (ws_size < need) return;  // insufficient scratch -> fail loudly (wrong out)

    float* WT   = ws;
    float* P    = ws + 360000;
    float* c    = ws + 1588800;
    float* s2   = ws + 1598400;
    unsigned short* hdec = (unsigned short*)(ws + 1608000);

    transpose4<<<dim3(10, 10, 4), dim3(32, 8), 0, stream>>>(
        enc_Wih, enc_Whh, dec_Wih, dec_Whh, WT);
    pproj<<<(BB * S_SRC) / RPB, 192, 0, stream>>>(x, EN, WT, enc_bih, enc_bhh, P);
    encoder<<<BB, 192, 0, stream>>>(h0, P, WT + 90000, c);
    sdec<<<BB, 192, 0, stream>>>(c, WT + 270000, dec_bih, dec_bhh, s2);
    hdec_k<<<M_ROWS / RPB, 192, 0, stream>>>(y, ZH, WT + 180000, s2, hdec);
    gemm_out<<<dim3(VV / BN, M_ROWS / BM), 256, 0, stream>>>(hdec, W_out, b_out, out);
}

// Round 2
// 402.359 us; speedup vs baseline: 3.7940x; 3.7940x over previous
//
#include <hip/hip_runtime.h>
#include <hip/hip_bf16.h>
#include <stdint.h>

#define BB 32
#define S_SRC 128
#define S_TGT 64
#define H 300
#define VV 32000
#define M_ROWS (BB * S_TGT)   // 2048
#define KP 320                // K padded to multiple of 32

typedef __attribute__((ext_vector_type(8))) __bf16 bf16x8;
typedef __attribute__((ext_vector_type(4))) float f32x4;

__device__ inline unsigned short f2bf(float f) {
    union { float f; unsigned u; } v; v.f = f;
    unsigned r = (v.u + 0x7FFF + ((v.u >> 16) & 1)) >> 16;  // RNE
    return (unsigned short)r;
}

// ---------------- transpose the four HxH weight matrices -> ws ----------------
__global__ void transpose4(const float* W0, const float* W1, const float* W2,
                           const float* W3, float* dst) {
    const float* srcs[4] = {W0, W1, W2, W3};
    const float* src = srcs[blockIdx.z];
    float* d = dst + (size_t)blockIdx.z * (H * H);
    __shared__ float tile[32][33];
    int j0 = blockIdx.y * 32, k0 = blockIdx.x * 32;
    for (int r = threadIdx.y; r < 32; r += blockDim.y) {
        int j = j0 + r, k = k0 + threadIdx.x;
        tile[r][threadIdx.x] = (j < H && k < H) ? src[(size_t)j * H + k] : 0.f;
    }
    __syncthreads();
    for (int r = threadIdx.y; r < 32; r += blockDim.y) {
        int k = k0 + r, j = j0 + threadIdx.x;
        if (k < H && j < H) d[(size_t)k * H + j] = tile[threadIdx.x][r];
    }
}

// ---------------- P[m][j] = EN[x[m]] @ WihT + bih + bhh  (m = b*128+t) --------
#define RPB 8
__global__ __launch_bounds__(192) void pproj(const int* __restrict__ x,
                                             const float* __restrict__ EN,
                                             const float* __restrict__ WihT,
                                             const float* __restrict__ bih,
                                             const float* __restrict__ bhh,
                                             float* __restrict__ P) {
    __shared__ float xe[RPB][H];
    int m0 = blockIdx.x * RPB;
    int tid = threadIdx.x;
    for (int r = 0; r < RPB; ++r) {
        int idx = x[m0 + r];
        for (int c = tid; c < H; c += 192) xe[r][c] = EN[(size_t)idx * H + c];
    }
    __syncthreads();
    if (tid < 150) {
        int j = tid * 2;
        float a0[RPB], a1[RPB];
#pragma unroll
        for (int r = 0; r < RPB; ++r) { a0[r] = 0.f; a1[r] = 0.f; }
        const float* wp = WihT + j;
        for (int k = 0; k < H; ++k) {
            float2 w = *reinterpret_cast<const float2*>(wp + (size_t)k * H);
#pragma unroll
            for (int r = 0; r < RPB; ++r) {
                float xv = xe[r][k];
                a0[r] += xv * w.x; a1[r] += xv * w.y;
            }
        }
        float b0 = bih[j] + bhh[j], b1 = bih[j + 1] + bhh[j + 1];
#pragma unroll
        for (int r = 0; r < RPB; ++r) {
            P[(size_t)(m0 + r) * H + j]     = a0[r] + b0;
            P[(size_t)(m0 + r) * H + j + 1] = a1[r] + b1;
        }
    }
}

// ---------------- encoder recurrence: h = tanh(P[t] + h @ Whh^T) --------------
// Whh kept in REGISTERS (rows, no transpose needed): thread (s, jp) owns
// rows {2jp, 2jp+1}, k-slice [100s, 100s+100). h in LDS, broadcast reads.
#define ENC_T 512
__global__ __launch_bounds__(ENC_T, 2) void encoder2(const float* __restrict__ h0,
                                                     const float* __restrict__ P,
                                                     const float* __restrict__ Whh,
                                                     float* __restrict__ c) {
    __shared__ float hbuf[304];
    __shared__ float part[3][304];
    int b = blockIdx.x, tid = threadIdx.x;
    int s = tid / 160;          // 0..3 (s==3 idle)
    int jp = tid - s * 160;     // 0..159 (jp>=150 idle)
    bool act = (s < 3) && (jp < 150);
    int j0 = jp * 2;

    float4 w0[25], w1[25];
    if (act) {
        const float* p0 = Whh + (size_t)j0 * H + s * 100;
        const float* p1 = p0 + H;
#pragma unroll
        for (int i = 0; i < 25; ++i) {
            w0[i] = *reinterpret_cast<const float4*>(p0 + i * 4);
            w1[i] = *reinterpret_cast<const float4*>(p1 + i * 4);
        }
    }
    for (int i = tid; i < H; i += ENC_T) hbuf[i] = h0[(size_t)b * H + i];
    __syncthreads();

    const float* Pb = P + (size_t)b * S_SRC * H;
    for (int t = 0; t < S_SRC; ++t) {
        float2 pv = make_float2(0.f, 0.f);
        if (s == 0 && jp < 150)   // prefetch P[t] (hides L2 latency under FMAs)
            pv = *reinterpret_cast<const float2*>(Pb + (size_t)t * H + j0);
        if (act) {
            float a0 = 0.f, a1 = 0.f;
            const float* hr = hbuf + s * 100;
#pragma unroll
            for (int i = 0; i < 25; ++i) {
                float4 hv = *reinterpret_cast<const float4*>(hr + i * 4);
                a0 += hv.x * w0[i].x; a1 += hv.x * w1[i].x;
                a0 += hv.y * w0[i].y; a1 += hv.y * w1[i].y;
                a0 += hv.z * w0[i].z; a1 += hv.z * w1[i].z;
                a0 += hv.w * w0[i].w; a1 += hv.w * w1[i].w;
            }
            *reinterpret_cast<float2*>(&part[s][j0]) = make_float2(a0, a1);
        }
        __syncthreads();
        if (s == 0 && jp < 150) {
            float s0 = part[0][j0]     + part[1][j0]     + part[2][j0]     + pv.x;
            float s1 = part[0][j0 + 1] + part[1][j0 + 1] + part[2][j0 + 1] + pv.y;
            *reinterpret_cast<float2*>(&hbuf[j0]) = make_float2(tanhf(s0), tanhf(s1));
        }
        __syncthreads();
    }
    for (int i = tid; i < H; i += ENC_T) c[(size_t)b * H + i] = hbuf[i];
}

// ---------------- s2[b][j] = c[b] @ WhhT_d + bhh_d + bih_d -------------------
__global__ __launch_bounds__(192) void sdec(const float* __restrict__ c,
                                            const float* __restrict__ WhhT_d,
                                            const float* __restrict__ bih_d,
                                            const float* __restrict__ bhh_d,
                                            float* __restrict__ s2) {
    __shared__ float cl[H];
    int b = blockIdx.x, tid = threadIdx.x;
    for (int k = tid; k < H; k += 192) cl[k] = c[(size_t)b * H + k];
    __syncthreads();
    if (tid < 150) {
        int j = tid * 2;
        float a0 = 0.f, a1 = 0.f;
        const float* wp = WhhT_d + j;
        for (int k = 0; k < H; ++k) {
            float2 w = *reinterpret_cast<const float2*>(wp + (size_t)k * H);
            a0 += cl[k] * w.x; a1 += cl[k] * w.y;
        }
        s2[(size_t)b * H + j]     = a0 + bih_d[j] + bhh_d[j];
        s2[(size_t)b * H + j + 1] = a1 + bih_d[j + 1] + bhh_d[j + 1];
    }
}

// ---------------- h_dec (bf16, K padded to 320): rows m = b*64+t -------------
__global__ __launch_bounds__(192) void hdec_k(const int* __restrict__ y,
                                              const float* __restrict__ ZH,
                                              const float* __restrict__ WihT_d,
                                              const float* __restrict__ s2,
                                              unsigned short* __restrict__ hdec) {
    __shared__ float ye[RPB][H];
    int m0 = blockIdx.x * RPB;
    int tid = threadIdx.x;
    for (int r = 0; r < RPB; ++r) {
        int idx = y[m0 + r];
        for (int c = tid; c < H; c += 192) ye[r][c] = ZH[(size_t)idx * H + c];
    }
    __syncthreads();
    if (tid < 150) {
        int j = tid * 2;
        float a0[RPB], a1[RPB];
#pragma unroll
        for (int r = 0; r < RPB; ++r) { a0[r] = 0.f; a1[r] = 0.f; }
        const float* wp = WihT_d + j;
        for (int k = 0; k < H; ++k) {
            float2 w = *reinterpret_cast<const float2*>(wp + (size_t)k * H);
#pragma unroll
            for (int r = 0; r < RPB; ++r) {
                float xv = ye[r][k];
                a0[r] += xv * w.x; a1[r] += xv * w.y;
            }
        }
#pragma unroll
        for (int r = 0; r < RPB; ++r) {
            int m = m0 + r;
            int b = m >> 6;
            float sv0 = s2[(size_t)b * H + j], sv1 = s2[(size_t)b * H + j + 1];
            hdec[(size_t)m * KP + j]     = f2bf(tanhf(a0[r] + sv0));
            hdec[(size_t)m * KP + j + 1] = f2bf(tanhf(a1[r] + sv1));
        }
    } else if (tid < 160) {
        int j = 300 + (tid - 150) * 2;   // zero the K padding 300..319
#pragma unroll
        for (int r = 0; r < RPB; ++r) {
            hdec[(size_t)(m0 + r) * KP + j]     = 0;
            hdec[(size_t)(m0 + r) * KP + j + 1] = 0;
        }
    }
}

// ---------------- out[2048,32000] = hdec @ W_out^T + b_out (bf16 MFMA) -------
#define BM 128
#define BN 128
#define BK 32
#define LDSW 40  // ushort row stride (80 B) -> breaks 64B-stride bank conflicts

__global__ __launch_bounds__(256) void gemm_out(const unsigned short* __restrict__ A,
                                                const float* __restrict__ W,
                                                const float* __restrict__ bout,
                                                float* __restrict__ out) {
    __shared__ __align__(16) unsigned short Alds[BM * LDSW];
    __shared__ __align__(16) unsigned short Blds[BN * LDSW];
    int tid = threadIdx.x;
    int lane = tid & 63, wv = tid >> 6;
    int wm = wv >> 1, wn = wv & 1;           // 2x2 waves, 64x64 each
    int m0 = blockIdx.y * BM, n0 = blockIdx.x * BN;

    f32x4 acc[4][4];
    f32x4 zero = {0.f, 0.f, 0.f, 0.f};
#pragma unroll
    for (int i = 0; i < 4; ++i)
#pragma unroll
        for (int jj = 0; jj < 4; ++jj) acc[i][jj] = zero;

    for (int k0 = 0; k0 < KP; k0 += BK) {
        // stage A tile [128][32] bf16 (already padded with zeros to K=320)
#pragma unroll
        for (int s = 0; s < 2; ++s) {
            int slot = tid + s * 256;
            int row = slot >> 2, c16 = slot & 3;
            uint4 v = *reinterpret_cast<const uint4*>(
                &A[(size_t)(m0 + row) * KP + k0 + c16 * 8]);
            *reinterpret_cast<uint4*>(&Alds[row * LDSW + c16 * 8]) = v;
        }
        // stage B tile [128][32]: rows of W_out (f32), convert to bf16, pad K>=300
#pragma unroll
        for (int s = 0; s < 2; ++s) {
            int slot = tid + s * 256;
            int row = slot >> 2, c8 = slot & 3;
            int k = k0 + c8 * 8;
            __align__(16) unsigned short tmp[8];
            if (k + 7 < H) {
                const float* src = &W[(size_t)(n0 + row) * H + k];
                float4 f0 = *reinterpret_cast<const float4*>(src);
                float4 f1 = *reinterpret_cast<const float4*>(src + 4);
                tmp[0] = f2bf(f0.x); tmp[1] = f2bf(f0.y);
                tmp[2] = f2bf(f0.z); tmp[3] = f2bf(f0.w);
                tmp[4] = f2bf(f1.x); tmp[5] = f2bf(f1.y);
                tmp[6] = f2bf(f1.z); tmp[7] = f2bf(f1.w);
            } else {
#pragma unroll
                for (int jv = 0; jv < 8; ++jv) {
                    int kk = k + jv;
                    tmp[jv] = (kk < H) ? f2bf(W[(size_t)(n0 + row) * H + kk])
                                       : (unsigned short)0;
                }
            }
            *reinterpret_cast<uint4*>(&Blds[row * LDSW + c8 * 8]) =
                *reinterpret_cast<const uint4*>(tmp);
        }
        __syncthreads();

        bf16x8 af[4], bfm[4];
#pragma unroll
        for (int i = 0; i < 4; ++i) {
            int row = wm * 64 + i * 16 + (lane & 15);
            af[i] = *reinterpret_cast<const bf16x8*>(&Alds[row * LDSW + (lane >> 4) * 8]);
        }
#pragma unroll
        for (int i = 0; i < 4; ++i) {
            int row = wn * 64 + i * 16 + (lane & 15);
            bfm[i] = *reinterpret_cast<const bf16x8*>(&Blds[row * LDSW + (lane >> 4) * 8]);
        }
#pragma unroll
        for (int i = 0; i < 4; ++i)
#pragma unroll
            for (int jj = 0; jj < 4; ++jj)
                acc[i][jj] = __builtin_amdgcn_mfma_f32_16x16x32_bf16(
                    af[i], bfm[jj], acc[i][jj], 0, 0, 0);
        __syncthreads();
    }

    // epilogue: D row=(lane>>4)*4+r, col=lane&15
#pragma unroll
    for (int jj = 0; jj < 4; ++jj) {
        int col = n0 + wn * 64 + jj * 16 + (lane & 15);
        float bo = bout[col];
#pragma unroll
        for (int i = 0; i < 4; ++i) {
            int rb = m0 + wm * 64 + i * 16 + (lane >> 4) * 4;
            f32x4 v = acc[i][jj];
#pragma unroll
            for (int r = 0; r < 4; ++r)
                out[(size_t)(rb + r) * VV + col] = v[r] + bo;
        }
    }
}

// ---------------- host ----------------
extern "C" void kernel_launch(void* const* d_in, const int* in_sizes, int n_in,
                              void* d_out, int out_size, void* d_ws, size_t ws_size,
                              hipStream_t stream) {
    const int*   x       = (const int*)d_in[0];
    const int*   y       = (const int*)d_in[1];
    const float* h0      = (const float*)d_in[2];
    const float* EN      = (const float*)d_in[3];
    const float* ZH      = (const float*)d_in[4];
    const float* enc_Wih = (const float*)d_in[5];
    const float* enc_Whh = (const float*)d_in[6];
    const float* enc_bih = (const float*)d_in[7];
    const float* enc_bhh = (const float*)d_in[8];
    const float* dec_Wih = (const float*)d_in[9];
    const float* dec_Whh = (const float*)d_in[10];
    const float* dec_bih = (const float*)d_in[11];
    const float* dec_bhh = (const float*)d_in[12];
    const float* W_out   = (const float*)d_in[13];
    const float* b_out   = (const float*)d_in[14];
    float* out = (float*)d_out;
    float* ws  = (float*)d_ws;

    // ws layout (f32 offsets):
    //   0        : WihT_enc (90000)
    //   90000    : WhhT_enc (unused now, kept for layout stability)
    //   180000   : WihT_dec
    //   270000   : WhhT_dec
    //   360000   : P [4096*300]
    //   1588800  : c [32*300]
    //   1598400  : s2 [32*300]
    //   1608000  : hdec bf16 [2048*320] (ushort)
    const size_t need = 1608000ull * 4 + (size_t)M_ROWS * KP * 2;
    if (ws_size < need) return;  // insufficient scratch -> fail loudly (wrong out)

    float* WT   = ws;
    float* P    = ws + 360000;
    float* c    = ws + 1588800;
    float* s2   = ws + 1598400;
    unsigned short* hdec = (unsigned short*)(ws + 1608000);

    transpose4<<<dim3(10, 10, 4), dim3(32, 8), 0, stream>>>(
        enc_Wih, enc_Whh, dec_Wih, dec_Whh, WT);
    pproj<<<(BB * S_SRC) / RPB, 192, 0, stream>>>(x, EN, WT, enc_bih, enc_bhh, P);
    encoder2<<<BB, ENC_T, 0, stream>>>(h0, P, enc_Whh, c);
    sdec<<<BB, 192, 0, stream>>>(c, WT + 270000, dec_bih, dec_bhh, s2);
    hdec_k<<<M_ROWS / RPB, 192, 0, stream>>>(y, ZH, WT + 180000, s2, hdec);
    gemm_out<<<dim3(VV / BN, M_ROWS / BM), 256, 0, stream>>>(hdec, W_out, b_out, out);
}

// Round 3
// 318.419 us; speedup vs baseline: 4.7941x; 1.2636x over previous
//
#include <hip/hip_runtime.h>
#include <hip/hip_bf16.h>
#include <stdint.h>

#define BB 32
#define S_SRC 128
#define S_TGT 64
#define H 300
#define VV 32000
#define M_ROWS (BB * S_TGT)   // 2048
#define KP 320                // K padded to multiple of 64

typedef __attribute__((ext_vector_type(8))) __bf16 bf16x8;
typedef __attribute__((ext_vector_type(4))) float f32x4;
typedef __attribute__((ext_vector_type(4))) unsigned short u16x4;

__device__ inline unsigned short f2bf(float f) {
    union { float f; unsigned u; } v; v.f = f;
    unsigned r = (v.u + 0x7FFF + ((v.u >> 16) & 1)) >> 16;  // RNE
    return (unsigned short)r;
}

__device__ __forceinline__ void gl_lds16(const void* g, void* l) {
    __builtin_amdgcn_global_load_lds(
        (const __attribute__((address_space(1))) void*)g,
        (__attribute__((address_space(3))) void*)l, 16, 0, 0);
}

// ---------------- transpose the four HxH weight matrices -> ws ----------------
__global__ void transpose4(const float* W0, const float* W1, const float* W2,
                           const float* W3, float* dst) {
    const float* srcs[4] = {W0, W1, W2, W3};
    const float* src = srcs[blockIdx.z];
    float* d = dst + (size_t)blockIdx.z * (H * H);
    __shared__ float tile[32][33];
    int j0 = blockIdx.y * 32, k0 = blockIdx.x * 32;
    for (int r = threadIdx.y; r < 32; r += blockDim.y) {
        int j = j0 + r, k = k0 + threadIdx.x;
        tile[r][threadIdx.x] = (j < H && k < H) ? src[(size_t)j * H + k] : 0.f;
    }
    __syncthreads();
    for (int r = threadIdx.y; r < 32; r += blockDim.y) {
        int k = k0 + r, j = j0 + threadIdx.x;
        if (k < H && j < H) d[(size_t)k * H + j] = tile[threadIdx.x][r];
    }
}

// ---------------- P[m][j] = EN[x[m]] @ WihT + bih + bhh  (m = b*128+t) --------
#define RPB 8
__global__ __launch_bounds__(192) void pproj(const int* __restrict__ x,
                                             const float* __restrict__ EN,
                                             const float* __restrict__ WihT,
                                             const float* __restrict__ bih,
                                             const float* __restrict__ bhh,
                                             float* __restrict__ P) {
    __shared__ float xe[RPB][H];
    int m0 = blockIdx.x * RPB;
    int tid = threadIdx.x;
    for (int r = 0; r < RPB; ++r) {
        int idx = x[m0 + r];
        for (int c = tid; c < H; c += 192) xe[r][c] = EN[(size_t)idx * H + c];
    }
    __syncthreads();
    if (tid < 150) {
        int j = tid * 2;
        float a0[RPB], a1[RPB];
#pragma unroll
        for (int r = 0; r < RPB; ++r) { a0[r] = 0.f; a1[r] = 0.f; }
        const float* wp = WihT + j;
        for (int k = 0; k < H; ++k) {
            float2 w = *reinterpret_cast<const float2*>(wp + (size_t)k * H);
#pragma unroll
            for (int r = 0; r < RPB; ++r) {
                float xv = xe[r][k];
                a0[r] += xv * w.x; a1[r] += xv * w.y;
            }
        }
        float b0 = bih[j] + bhh[j], b1 = bih[j + 1] + bhh[j + 1];
#pragma unroll
        for (int r = 0; r < RPB; ++r) {
            P[(size_t)(m0 + r) * H + j]     = a0[r] + b0;
            P[(size_t)(m0 + r) * H + j + 1] = a1[r] + b1;
        }
    }
}

// ---------------- encoder recurrence: h = tanh(P[t] + h @ Whh^T) --------------
#define ENC_T 512
__global__ __launch_bounds__(ENC_T, 2) void encoder2(const float* __restrict__ h0,
                                                     const float* __restrict__ P,
                                                     const float* __restrict__ Whh,
                                                     float* __restrict__ c) {
    __shared__ float hbuf[304];
    __shared__ float part[3][304];
    int b = blockIdx.x, tid = threadIdx.x;
    int s = tid / 160;          // 0..3 (s==3 idle)
    int jp = tid - s * 160;     // 0..159 (jp>=150 idle)
    bool act = (s < 3) && (jp < 150);
    int j0 = jp * 2;

    float4 w0[25], w1[25];
    if (act) {
        const float* p0 = Whh + (size_t)j0 * H + s * 100;
        const float* p1 = p0 + H;
#pragma unroll
        for (int i = 0; i < 25; ++i) {
            w0[i] = *reinterpret_cast<const float4*>(p0 + i * 4);
            w1[i] = *reinterpret_cast<const float4*>(p1 + i * 4);
        }
    }
    for (int i = tid; i < H; i += ENC_T) hbuf[i] = h0[(size_t)b * H + i];
    __syncthreads();

    const float* Pb = P + (size_t)b * S_SRC * H;
    for (int t = 0; t < S_SRC; ++t) {
        float2 pv = make_float2(0.f, 0.f);
        if (s == 0 && jp < 150)
            pv = *reinterpret_cast<const float2*>(Pb + (size_t)t * H + j0);
        if (act) {
            float a0 = 0.f, a1 = 0.f;
            const float* hr = hbuf + s * 100;
#pragma unroll
            for (int i = 0; i < 25; ++i) {
                float4 hv = *reinterpret_cast<const float4*>(hr + i * 4);
                a0 += hv.x * w0[i].x; a1 += hv.x * w1[i].x;
                a0 += hv.y * w0[i].y; a1 += hv.y * w1[i].y;
                a0 += hv.z * w0[i].z; a1 += hv.z * w1[i].z;
                a0 += hv.w * w0[i].w; a1 += hv.w * w1[i].w;
            }
            *reinterpret_cast<float2*>(&part[s][j0]) = make_float2(a0, a1);
        }
        __syncthreads();
        if (s == 0 && jp < 150) {
            float s0 = part[0][j0]     + part[1][j0]     + part[2][j0]     + pv.x;
            float s1 = part[0][j0 + 1] + part[1][j0 + 1] + part[2][j0 + 1] + pv.y;
            *reinterpret_cast<float2*>(&hbuf[j0]) = make_float2(tanhf(s0), tanhf(s1));
        }
        __syncthreads();
    }
    for (int i = tid; i < H; i += ENC_T) c[(size_t)b * H + i] = hbuf[i];
}

// ---------------- s2[b][j] = c[b] @ WhhT_d + bhh_d + bih_d -------------------
__global__ __launch_bounds__(192) void sdec(const float* __restrict__ c,
                                            const float* __restrict__ WhhT_d,
                                            const float* __restrict__ bih_d,
                                            const float* __restrict__ bhh_d,
                                            float* __restrict__ s2) {
    __shared__ float cl[H];
    int b = blockIdx.x, tid = threadIdx.x;
    for (int k = tid; k < H; k += 192) cl[k] = c[(size_t)b * H + k];
    __syncthreads();
    if (tid < 150) {
        int j = tid * 2;
        float a0 = 0.f, a1 = 0.f;
        const float* wp = WhhT_d + j;
        for (int k = 0; k < H; ++k) {
            float2 w = *reinterpret_cast<const float2*>(wp + (size_t)k * H);
            a0 += cl[k] * w.x; a1 += cl[k] * w.y;
        }
        s2[(size_t)b * H + j]     = a0 + bih_d[j] + bhh_d[j];
        s2[(size_t)b * H + j + 1] = a1 + bih_d[j + 1] + bhh_d[j + 1];
    }
}

// ---------------- h_dec (bf16, K padded to 320): rows m = b*64+t -------------
__global__ __launch_bounds__(192) void hdec_k(const int* __restrict__ y,
                                              const float* __restrict__ ZH,
                                              const float* __restrict__ WihT_d,
                                              const float* __restrict__ s2,
                                              unsigned short* __restrict__ hdec) {
    __shared__ float ye[RPB][H];
    int m0 = blockIdx.x * RPB;
    int tid = threadIdx.x;
    for (int r = 0; r < RPB; ++r) {
        int idx = y[m0 + r];
        for (int c = tid; c < H; c += 192) ye[r][c] = ZH[(size_t)idx * H + c];
    }
    __syncthreads();
    if (tid < 150) {
        int j = tid * 2;
        float a0[RPB], a1[RPB];
#pragma unroll
        for (int r = 0; r < RPB; ++r) { a0[r] = 0.f; a1[r] = 0.f; }
        const float* wp = WihT_d + j;
        for (int k = 0; k < H; ++k) {
            float2 w = *reinterpret_cast<const float2*>(wp + (size_t)k * H);
#pragma unroll
            for (int r = 0; r < RPB; ++r) {
                float xv = ye[r][k];
                a0[r] += xv * w.x; a1[r] += xv * w.y;
            }
        }
#pragma unroll
        for (int r = 0; r < RPB; ++r) {
            int m = m0 + r;
            int b = m >> 6;
            float sv0 = s2[(size_t)b * H + j], sv1 = s2[(size_t)b * H + j + 1];
            hdec[(size_t)m * KP + j]     = f2bf(tanhf(a0[r] + sv0));
            hdec[(size_t)m * KP + j + 1] = f2bf(tanhf(a1[r] + sv1));
        }
    } else if (tid < 160) {
        int j = 300 + (tid - 150) * 2;   // zero the K padding 300..319
#pragma unroll
        for (int r = 0; r < RPB; ++r) {
            hdec[(size_t)(m0 + r) * KP + j]     = 0;
            hdec[(size_t)(m0 + r) * KP + j + 1] = 0;
        }
    }
}

// ---------------- W_out f32 [32000x300] -> bf16 [32000x320] zero-padded ------
__global__ __launch_bounds__(256) void wcvt(const float* __restrict__ W,
                                            unsigned short* __restrict__ Wb) {
    int id = blockIdx.x * 256 + threadIdx.x;   // 32000*80
    int row = id / 80, c = id - row * 80;
    int k = c * 4;
    u16x4 o;
    if (k < H) {
        float4 f = *reinterpret_cast<const float4*>(W + (size_t)row * H + k);
        o[0] = f2bf(f.x); o[1] = f2bf(f.y); o[2] = f2bf(f.z); o[3] = f2bf(f.w);
    } else {
        o[0] = 0; o[1] = 0; o[2] = 0; o[3] = 0;
    }
    *reinterpret_cast<u16x4*>(Wb + (size_t)row * KP + k) = o;
}

// ---------------- out = hdec[2048,320] @ Wb[32000,320]^T + b_out -------------
// m97-structure: 128x128 tile, BK=64, dbuf LDS, global_load_lds w16,
// XOR(row&7) chunk swizzle pre-applied on the GLOBAL source (rule #21),
// XCD-bijective block swizzle, m-fastest (16 m-panels share each W panel).
__global__ __launch_bounds__(256) void gemm2(const unsigned short* __restrict__ A,
                                             const unsigned short* __restrict__ Wb,
                                             const float* __restrict__ bout,
                                             float* __restrict__ out) {
    __shared__ unsigned short Al[2][128 * 64];
    __shared__ unsigned short Blds[2][128 * 64];
    int tid = threadIdx.x;
    int lane = tid & 63, wv = tid >> 6;
    int wm = wv >> 1, wn = wv & 1;           // 2x2 waves, 64x64 each

    int orig = blockIdx.x;                    // 4000 blocks
    int wg = (orig & 7) * 500 + (orig >> 3);  // bijective XCD swizzle (4000%8==0)
    int mi = wg & 15, ni = wg >> 4;           // m-fastest
    int m0 = mi * 128, n0 = ni * 128;

    // staging coords: slot = i*256+tid; row = i*32 + (tid>>3); chunk = tid&7
    int rowb = tid >> 3;
    int sc2 = (tid & 7) ^ (rowb & 7);         // pre-swizzled source chunk

    f32x4 acc[4][4];
    f32x4 zero = {0.f, 0.f, 0.f, 0.f};
#pragma unroll
    for (int i = 0; i < 4; ++i)
#pragma unroll
        for (int j = 0; j < 4; ++j) acc[i][j] = zero;

    // prologue stage k-tile 0 into buf 0
#pragma unroll
    for (int i = 0; i < 4; ++i) {
        int row = i * 32 + rowb;
        gl_lds16(A + (size_t)(m0 + row) * KP + sc2 * 8, &Al[0][(i * 256 + tid) * 8]);
    }
#pragma unroll
    for (int i = 0; i < 4; ++i) {
        int row = i * 32 + rowb;
        gl_lds16(Wb + (size_t)(n0 + row) * KP + sc2 * 8, &Blds[0][(i * 256 + tid) * 8]);
    }

    for (int t = 0; t < 5; ++t) {
        __syncthreads();   // drains vmcnt: stage(t) visible; prev reads done
        int buf = t & 1;
        bf16x8 af[2][4], bb[2][4];
#pragma unroll
        for (int ks = 0; ks < 2; ++ks)
#pragma unroll
            for (int i = 0; i < 4; ++i) {
                int ch = (ks * 4 + (lane >> 4)) ^ (lane & 7);  // read-side XOR
                int rowA = wm * 64 + i * 16 + (lane & 15);
                af[ks][i] = *reinterpret_cast<const bf16x8*>(&Al[buf][rowA * 64 + ch * 8]);
                int rowB = wn * 64 + i * 16 + (lane & 15);
                bb[ks][i] = *reinterpret_cast<const bf16x8*>(&Blds[buf][rowB * 64 + ch * 8]);
            }
        if (t < 4) {   // prefetch next k-tile; latency hides under the MFMAs
            int k0 = (t + 1) * 64, nb = buf ^ 1;
#pragma unroll
            for (int i = 0; i < 4; ++i) {
                int row = i * 32 + rowb;
                gl_lds16(A + (size_t)(m0 + row) * KP + k0 + sc2 * 8,
                         &Al[nb][(i * 256 + tid) * 8]);
            }
#pragma unroll
            for (int i = 0; i < 4; ++i) {
                int row = i * 32 + rowb;
                gl_lds16(Wb + (size_t)(n0 + row) * KP + k0 + sc2 * 8,
                         &Blds[nb][(i * 256 + tid) * 8]);
            }
        }
#pragma unroll
        for (int ks = 0; ks < 2; ++ks)
#pragma unroll
            for (int i = 0; i < 4; ++i)
#pragma unroll
                for (int j = 0; j < 4; ++j)
                    acc[i][j] = __builtin_amdgcn_mfma_f32_16x16x32_bf16(
                        af[ks][i], bb[ks][j], acc[i][j], 0, 0, 0);
    }

    // epilogue: D row=(lane>>4)*4+r, col=lane&15
#pragma unroll
    for (int j = 0; j < 4; ++j) {
        int col = n0 + wn * 64 + j * 16 + (lane & 15);
        float bo = bout[col];
#pragma unroll
        for (int i = 0; i < 4; ++i) {
            int rb = m0 + wm * 64 + i * 16 + (lane >> 4) * 4;
            f32x4 v = acc[i][j];
#pragma unroll
            for (int r = 0; r < 4; ++r)
                out[(size_t)(rb + r) * VV + col] = v[r] + bo;
        }
    }
}

// ---------------- fallback GEMM (reads W f32) for small ws -------------------
#define LDSW 40
__global__ __launch_bounds__(256) void gemm_out(const unsigned short* __restrict__ A,
                                                const float* __restrict__ W,
                                                const float* __restrict__ bout,
                                                float* __restrict__ out) {
    __shared__ __align__(16) unsigned short Alds[128 * LDSW];
    __shared__ __align__(16) unsigned short Bl[128 * LDSW];
    int tid = threadIdx.x;
    int lane = tid & 63, wv = tid >> 6;
    int wm = wv >> 1, wn = wv & 1;
    int m0 = blockIdx.y * 128, n0 = blockIdx.x * 128;

    f32x4 acc[4][4];
    f32x4 zero = {0.f, 0.f, 0.f, 0.f};
#pragma unroll
    for (int i = 0; i < 4; ++i)
#pragma unroll
        for (int jj = 0; jj < 4; ++jj) acc[i][jj] = zero;

    for (int k0 = 0; k0 < KP; k0 += 32) {
#pragma unroll
        for (int s = 0; s < 2; ++s) {
            int slot = tid + s * 256;
            int row = slot >> 2, c16 = slot & 3;
            uint4 v = *reinterpret_cast<const uint4*>(
                &A[(size_t)(m0 + row) * KP + k0 + c16 * 8]);
            *reinterpret_cast<uint4*>(&Alds[row * LDSW + c16 * 8]) = v;
        }
#pragma unroll
        for (int s = 0; s < 2; ++s) {
            int slot = tid + s * 256;
            int row = slot >> 2, c8 = slot & 3;
            int k = k0 + c8 * 8;
            __align__(16) unsigned short tmp[8];
            if (k + 7 < H) {
                const float* src = &W[(size_t)(n0 + row) * H + k];
                float4 f0 = *reinterpret_cast<const float4*>(src);
                float4 f1 = *reinterpret_cast<const float4*>(src + 4);
                tmp[0] = f2bf(f0.x); tmp[1] = f2bf(f0.y);
                tmp[2] = f2bf(f0.z); tmp[3] = f2bf(f0.w);
                tmp[4] = f2bf(f1.x); tmp[5] = f2bf(f1.y);
                tmp[6] = f2bf(f1.z); tmp[7] = f2bf(f1.w);
            } else {
#pragma unroll
                for (int jv = 0; jv < 8; ++jv) {
                    int kk = k + jv;
                    tmp[jv] = (kk < H) ? f2bf(W[(size_t)(n0 + row) * H + kk])
                                       : (unsigned short)0;
                }
            }
            *reinterpret_cast<uint4*>(&Bl[row * LDSW + c8 * 8]) =
                *reinterpret_cast<const uint4*>(tmp);
        }
        __syncthreads();
        bf16x8 af[4], bfm[4];
#pragma unroll
        for (int i = 0; i < 4; ++i) {
            int row = wm * 64 + i * 16 + (lane & 15);
            af[i] = *reinterpret_cast<const bf16x8*>(&Alds[row * LDSW + (lane >> 4) * 8]);
        }
#pragma unroll
        for (int i = 0; i < 4; ++i) {
            int row = wn * 64 + i * 16 + (lane & 15);
            bfm[i] = *reinterpret_cast<const bf16x8*>(&Bl[row * LDSW + (lane >> 4) * 8]);
        }
#pragma unroll
        for (int i = 0; i < 4; ++i)
#pragma unroll
            for (int jj = 0; jj < 4; ++jj)
                acc[i][jj] = __builtin_amdgcn_mfma_f32_16x16x32_bf16(
                    af[i], bfm[jj], acc[i][jj], 0, 0, 0);
        __syncthreads();
    }
#pragma unroll
    for (int jj = 0; jj < 4; ++jj) {
        int col = n0 + wn * 64 + jj * 16 + (lane & 15);
        float bo = bout[col];
#pragma unroll
        for (int i = 0; i < 4; ++i) {
            int rb = m0 + wm * 64 + i * 16 + (lane >> 4) * 4;
            f32x4 v = acc[i][jj];
#pragma unroll
            for (int r = 0; r < 4; ++r)
                out[(size_t)(rb + r) * VV + col] = v[r] + bo;
        }
    }
}

// ---------------- host ----------------
extern "C" void kernel_launch(void* const* d_in, const int* in_sizes, int n_in,
                              void* d_out, int out_size, void* d_ws, size_t ws_size,
                              hipStream_t stream) {
    const int*   x       = (const int*)d_in[0];
    const int*   y       = (const int*)d_in[1];
    const float* h0      = (const float*)d_in[2];
    const float* EN      = (const float*)d_in[3];
    const float* ZH      = (const float*)d_in[4];
    const float* enc_Wih = (const float*)d_in[5];
    const float* enc_Whh = (const float*)d_in[6];
    const float* enc_bih = (const float*)d_in[7];
    const float* enc_bhh = (const float*)d_in[8];
    const float* dec_Wih = (const float*)d_in[9];
    const float* dec_Whh = (const float*)d_in[10];
    const float* dec_bih = (const float*)d_in[11];
    const float* dec_bhh = (const float*)d_in[12];
    const float* W_out   = (const float*)d_in[13];
    const float* b_out   = (const float*)d_in[14];
    float* out = (float*)d_out;
    char* base = (char*)d_ws;

    // byte layout:
    //   0        : WT (4x 90000 f32 = 1,440,000)
    //   1,440,000: union { P [4096x300 f32 = 4,915,200] ; Wb [32000x320 bf16 = 20,480,000] }
    //             (P dead after encoder2; wcvt runs after encoder2)
    // big path:
    //   21,920,000: c ; 21,958,400: s2 ; 21,996,800: hdec [2048x320 u16]
    // small path (no Wb):
    //   6,355,200: c ; 6,393,600: s2 ; 6,432,000: hdec
    const size_t needA = 23307520, needB = 7742720;
    bool bigws = (ws_size >= needA);
    if (!bigws && ws_size < needB) return;

    float* WT = (float*)base;
    float* P  = (float*)(base + 1440000);
    float *c_, *s2_;
    unsigned short *hdec, *Wb = nullptr;
    if (bigws) {
        Wb   = (unsigned short*)(base + 1440000);
        c_   = (float*)(base + 21920000);
        s2_  = (float*)(base + 21958400);
        hdec = (unsigned short*)(base + 21996800);
    } else {
        c_   = (float*)(base + 6355200);
        s2_  = (float*)(base + 6393600);
        hdec = (unsigned short*)(base + 6432000);
    }

    transpose4<<<dim3(10, 10, 4), dim3(32, 8), 0, stream>>>(
        enc_Wih, enc_Whh, dec_Wih, dec_Whh, WT);
    pproj<<<(BB * S_SRC) / RPB, 192, 0, stream>>>(x, EN, WT, enc_bih, enc_bhh, P);
    encoder2<<<BB, ENC_T, 0, stream>>>(h0, P, enc_Whh, c_);
    sdec<<<BB, 192, 0, stream>>>(c_, WT + 270000, dec_bih, dec_bhh, s2_);
    hdec_k<<<M_ROWS / RPB, 192, 0, stream>>>(y, ZH, WT + 180000, s2_, hdec);
    if (bigws) {
        wcvt<<<(VV * 80) / 256, 256, 0, stream>>>(W_out, Wb);
        gemm2<<<4000, 256, 0, stream>>>(hdec, Wb, b_out, out);
    } else {
        gemm_out<<<dim3(VV / 128, M_ROWS / 128), 256, 0, stream>>>(hdec, W_out, b_out, out);
    }
}

// Round 5
// 279.828 us; speedup vs baseline: 5.4553x; 1.1379x over previous
//
#include <hip/hip_runtime.h>
#include <hip/hip_bf16.h>
#include <stdint.h>

#define BB 32
#define S_SRC 128
#define S_TGT 64
#define H 300
#define VV 32000
#define M_ROWS (BB * S_TGT)   // 2048
#define KP 320                // K padded to multiple of 64

typedef __attribute__((ext_vector_type(8))) __bf16 bf16x8;
typedef __attribute__((ext_vector_type(4))) float f32x4;
typedef __attribute__((ext_vector_type(4))) unsigned short u16x4;
typedef __attribute__((ext_vector_type(2))) __fp16 f16x2;   // matches cvt_pkrtz/fdot2

#if defined(__has_builtin)
#if __has_builtin(__builtin_amdgcn_fdot2)
#define HAVE_FDOT2 1
#endif
#endif

__device__ inline unsigned short f2bf(float f) {
    union { float f; unsigned u; } v; v.f = f;
    unsigned r = (v.u + 0x7FFF + ((v.u >> 16) & 1)) >> 16;  // RNE
    return (unsigned short)r;
}

__device__ __forceinline__ float ftanh(float x) {
    // tanh(x) = 1 - 2/(exp2(x*2*log2e)+1); exp2/rcp are HW transcendentals.
    float e = __builtin_amdgcn_exp2f(x * 2.8853900817779268f);
    return 1.0f - 2.0f * __builtin_amdgcn_rcpf(e + 1.0f);
}

__device__ __forceinline__ float fdot2(f16x2 a, f16x2 b, float c) {
#ifdef HAVE_FDOT2
    return __builtin_amdgcn_fdot2(a, b, c, false);
#else
    return c + (float)a.x * (float)b.x + (float)a.y * (float)b.y;
#endif
}

__device__ __forceinline__ void gl_lds16(const void* g, void* l) {
    __builtin_amdgcn_global_load_lds(
        (const __attribute__((address_space(1))) void*)g,
        (__attribute__((address_space(3))) void*)l, 16, 0, 0);
}

// ---------------- transpose the four HxH weight matrices -> ws ----------------
__global__ void transpose4(const float* W0, const float* W1, const float* W2,
                           const float* W3, float* dst) {
    const float* srcs[4] = {W0, W1, W2, W3};
    const float* src = srcs[blockIdx.z];
    float* d = dst + (size_t)blockIdx.z * (H * H);
    __shared__ float tile[32][33];
    int j0 = blockIdx.y * 32, k0 = blockIdx.x * 32;
    for (int r = threadIdx.y; r < 32; r += blockDim.y) {
        int j = j0 + r, k = k0 + threadIdx.x;
        tile[r][threadIdx.x] = (j < H && k < H) ? src[(size_t)j * H + k] : 0.f;
    }
    __syncthreads();
    for (int r = threadIdx.y; r < 32; r += blockDim.y) {
        int k = k0 + r, j = j0 + threadIdx.x;
        if (k < H && j < H) d[(size_t)k * H + j] = tile[threadIdx.x][r];
    }
}

// ---------------- P[m][j] = EN[x[m]] @ WihT + bih + bhh  (m = b*128+t) --------
#define RPB 8
__global__ __launch_bounds__(192) void pproj(const int* __restrict__ x,
                                             const float* __restrict__ EN,
                                             const float* __restrict__ WihT,
                                             const float* __restrict__ bih,
                                             const float* __restrict__ bhh,
                                             float* __restrict__ P) {
    __shared__ float xe[RPB][H];
    int m0 = blockIdx.x * RPB;
    int tid = threadIdx.x;
    for (int r = 0; r < RPB; ++r) {
        int idx = x[m0 + r];
        for (int c = tid; c < H; c += 192) xe[r][c] = EN[(size_t)idx * H + c];
    }
    __syncthreads();
    if (tid < 150) {
        int j = tid * 2;
        float a0[RPB], a1[RPB];
#pragma unroll
        for (int r = 0; r < RPB; ++r) { a0[r] = 0.f; a1[r] = 0.f; }
        const float* wp = WihT + j;
        for (int k = 0; k < H; ++k) {
            float2 w = *reinterpret_cast<const float2*>(wp + (size_t)k * H);
#pragma unroll
            for (int r = 0; r < RPB; ++r) {
                float xv = xe[r][k];
                a0[r] += xv * w.x; a1[r] += xv * w.y;
            }
        }
        float b0 = bih[j] + bhh[j], b1 = bih[j + 1] + bhh[j + 1];
#pragma unroll
        for (int r = 0; r < RPB; ++r) {
            P[(size_t)(m0 + r) * H + j]     = a0[r] + b0;
            P[(size_t)(m0 + r) * H + j + 1] = a1[r] + b1;
        }
    }
}

// ---------------- encoder recurrence: h = tanh(P[t] + h @ Whh^T) --------------
// f16 dot2 version: thread (s,jp) owns rows {2jp,2jp+1}, k-slice [100s,100s+100)
// as 100 f16x2 VGPRs; h lives in LDS as packed f16x2 (broadcast uint2 reads).
// 150 reducer threads (jp<50 per slice) sum 3 partials + P, fast-tanh, repack.
#define ENC_T 512
__global__ __launch_bounds__(ENC_T, 2) void encoder3(const float* __restrict__ h0,
                                                     const float* __restrict__ P,
                                                     const float* __restrict__ Whh,
                                                     float* __restrict__ c) {
    __shared__ __align__(16) f16x2 hbuf2[160];   // 150 used
    __shared__ __align__(16) float part[3][304];
    int b = blockIdx.x, tid = threadIdx.x;
    int s = tid / 160;          // 0..3 (s==3 idle)
    int jp = tid - s * 160;     // 0..159 (jp>=150 idle)
    bool act = (s < 3) && (jp < 150);
    int j0 = jp * 2;
    int jq = s * 50 + jp;       // reducer's j-pair
    bool red = (s < 3) && (jp < 50);

    f16x2 w0[50], w1[50];
    if (act) {
        const float* p0 = Whh + (size_t)j0 * H + s * 100;
        const float* p1 = p0 + H;
#pragma unroll
        for (int i = 0; i < 25; ++i) {
            float4 f0 = *reinterpret_cast<const float4*>(p0 + i * 4);
            float4 f1 = *reinterpret_cast<const float4*>(p1 + i * 4);
            w0[2 * i]     = __builtin_amdgcn_cvt_pkrtz(f0.x, f0.y);
            w0[2 * i + 1] = __builtin_amdgcn_cvt_pkrtz(f0.z, f0.w);
            w1[2 * i]     = __builtin_amdgcn_cvt_pkrtz(f1.x, f1.y);
            w1[2 * i + 1] = __builtin_amdgcn_cvt_pkrtz(f1.z, f1.w);
        }
    }
    if (red) {
        float2 hv = *reinterpret_cast<const float2*>(h0 + (size_t)b * H + 2 * jq);
        hbuf2[jq] = __builtin_amdgcn_cvt_pkrtz(hv.x, hv.y);
    }
    __syncthreads();

    const float* Pb = P + (size_t)b * S_SRC * H;
    for (int t = 0; t < S_SRC; ++t) {
        float2 pv = make_float2(0.f, 0.f);
        if (red)   // issue early; latency hides under the dot phase
            pv = *reinterpret_cast<const float2*>(Pb + (size_t)t * H + 2 * jq);
        if (act) {
            float a0 = 0.f, a1 = 0.f;
            const uint2* hp = reinterpret_cast<const uint2*>(hbuf2 + s * 50);
#pragma unroll
            for (int i = 0; i < 25; ++i) {
                uint2 u = hp[i];
                f16x2 h0v = __builtin_bit_cast(f16x2, u.x);
                f16x2 h1v = __builtin_bit_cast(f16x2, u.y);
                a0 = fdot2(w0[2 * i], h0v, a0);
                a0 = fdot2(w0[2 * i + 1], h1v, a0);
                a1 = fdot2(w1[2 * i], h0v, a1);
                a1 = fdot2(w1[2 * i + 1], h1v, a1);
            }
            *reinterpret_cast<float2*>(&part[s][j0]) = make_float2(a0, a1);
        }
        __syncthreads();
        if (red) {
            float2 q0 = *reinterpret_cast<const float2*>(&part[0][2 * jq]);
            float2 q1 = *reinterpret_cast<const float2*>(&part[1][2 * jq]);
            float2 q2 = *reinterpret_cast<const float2*>(&part[2][2 * jq]);
            float s0 = q0.x + q1.x + q2.x + pv.x;
            float s1 = q0.y + q1.y + q2.y + pv.y;
            hbuf2[jq] = __builtin_amdgcn_cvt_pkrtz(ftanh(s0), ftanh(s1));
        }
        __syncthreads();
    }
    if (red) {
        f16x2 hv = hbuf2[jq];
        *reinterpret_cast<float2*>(c + (size_t)b * H + 2 * jq) =
            make_float2((float)hv.x, (float)hv.y);
    }
}

// ---------------- s2[b][j] = c[b] @ WhhT_d + bhh_d + bih_d -------------------
__global__ __launch_bounds__(192) void sdec(const float* __restrict__ c,
                                            const float* __restrict__ WhhT_d,
                                            const float* __restrict__ bih_d,
                                            const float* __restrict__ bhh_d,
                                            float* __restrict__ s2) {
    __shared__ float cl[H];
    int b = blockIdx.x, tid = threadIdx.x;
    for (int k = tid; k < H; k += 192) cl[k] = c[(size_t)b * H + k];
    __syncthreads();
    if (tid < 150) {
        int j = tid * 2;
        float a0 = 0.f, a1 = 0.f;
        const float* wp = WhhT_d + j;
        for (int k = 0; k < H; ++k) {
            float2 w = *reinterpret_cast<const float2*>(wp + (size_t)k * H);
            a0 += cl[k] * w.x; a1 += cl[k] * w.y;
        }
        s2[(size_t)b * H + j]     = a0 + bih_d[j] + bhh_d[j];
        s2[(size_t)b * H + j + 1] = a1 + bih_d[j + 1] + bhh_d[j + 1];
    }
}

// ---------------- h_dec (bf16, K padded to 320): rows m = b*64+t -------------
__global__ __launch_bounds__(192) void hdec_k(const int* __restrict__ y,
                                              const float* __restrict__ ZH,
                                              const float* __restrict__ WihT_d,
                                              const float* __restrict__ s2,
                                              unsigned short* __restrict__ hdec) {
    __shared__ float ye[RPB][H];
    int m0 = blockIdx.x * RPB;
    int tid = threadIdx.x;
    for (int r = 0; r < RPB; ++r) {
        int idx = y[m0 + r];
        for (int c = tid; c < H; c += 192) ye[r][c] = ZH[(size_t)idx * H + c];
    }
    __syncthreads();
    if (tid < 150) {
        int j = tid * 2;
        float a0[RPB], a1[RPB];
#pragma unroll
        for (int r = 0; r < RPB; ++r) { a0[r] = 0.f; a1[r] = 0.f; }
        const float* wp = WihT_d + j;
        for (int k = 0; k < H; ++k) {
            float2 w = *reinterpret_cast<const float2*>(wp + (size_t)k * H);
#pragma unroll
            for (int r = 0; r < RPB; ++r) {
                float xv = ye[r][k];
                a0[r] += xv * w.x; a1[r] += xv * w.y;
            }
        }
#pragma unroll
        for (int r = 0; r < RPB; ++r) {
            int m = m0 + r;
            int b = m >> 6;
            float sv0 = s2[(size_t)b * H + j], sv1 = s2[(size_t)b * H + j + 1];
            hdec[(size_t)m * KP + j]     = f2bf(ftanh(a0[r] + sv0));
            hdec[(size_t)m * KP + j + 1] = f2bf(ftanh(a1[r] + sv1));
        }
    } else if (tid < 160) {
        int j = 300 + (tid - 150) * 2;   // zero the K padding 300..319
#pragma unroll
        for (int r = 0; r < RPB; ++r) {
            hdec[(size_t)(m0 + r) * KP + j]     = 0;
            hdec[(size_t)(m0 + r) * KP + j + 1] = 0;
        }
    }
}

// ---------------- W_out f32 [32000x300] -> bf16 [32000x320] zero-padded ------
__global__ __launch_bounds__(256) void wcvt(const float* __restrict__ W,
                                            unsigned short* __restrict__ Wb) {
    int id = blockIdx.x * 256 + threadIdx.x;   // 32000*80
    int row = id / 80, c = id - row * 80;
    int k = c * 4;
    u16x4 o;
    if (k < H) {
        float4 f = *reinterpret_cast<const float4*>(W + (size_t)row * H + k);
        o[0] = f2bf(f.x); o[1] = f2bf(f.y); o[2] = f2bf(f.z); o[3] = f2bf(f.w);
    } else {
        o[0] = 0; o[1] = 0; o[2] = 0; o[3] = 0;
    }
    *reinterpret_cast<u16x4*>(Wb + (size_t)row * KP + k) = o;
}

// ---------------- out = hdec[2048,320] @ Wb[32000,320]^T + b_out -------------
__global__ __launch_bounds__(256) void gemm2(const unsigned short* __restrict__ A,
                                             const unsigned short* __restrict__ Wb,
                                             const float* __restrict__ bout,
                                             float* __restrict__ out) {
    __shared__ unsigned short Al[2][128 * 64];
    __shared__ unsigned short Blds[2][128 * 64];
    int tid = threadIdx.x;
    int lane = tid & 63, wv = tid >> 6;
    int wm = wv >> 1, wn = wv & 1;           // 2x2 waves, 64x64 each

    int orig = blockIdx.x;                    // 4000 blocks
    int wg = (orig & 7) * 500 + (orig >> 3);  // bijective XCD swizzle (4000%8==0)
    int mi = wg & 15, ni = wg >> 4;           // m-fastest
    int m0 = mi * 128, n0 = ni * 128;

    int rowb = tid >> 3;
    int sc2 = (tid & 7) ^ (rowb & 7);         // pre-swizzled source chunk

    f32x4 acc[4][4];
    f32x4 zero = {0.f, 0.f, 0.f, 0.f};
#pragma unroll
    for (int i = 0; i < 4; ++i)
#pragma unroll
        for (int j = 0; j < 4; ++j) acc[i][j] = zero;

    // prologue stage k-tile 0 into buf 0
#pragma unroll
    for (int i = 0; i < 4; ++i) {
        int row = i * 32 + rowb;
        gl_lds16(A + (size_t)(m0 + row) * KP + sc2 * 8, &Al[0][(i * 256 + tid) * 8]);
    }
#pragma unroll
    for (int i = 0; i < 4; ++i) {
        int row = i * 32 + rowb;
        gl_lds16(Wb + (size_t)(n0 + row) * KP + sc2 * 8, &Blds[0][(i * 256 + tid) * 8]);
    }

    for (int t = 0; t < 5; ++t) {
        __syncthreads();   // drains vmcnt: stage(t) visible; prev reads done
        int buf = t & 1;
        if (t < 4) {   // prefetch FIRST: max latency cover before next barrier
            int k0 = (t + 1) * 64, nb = buf ^ 1;
#pragma unroll
            for (int i = 0; i < 4; ++i) {
                int row = i * 32 + rowb;
                gl_lds16(A + (size_t)(m0 + row) * KP + k0 + sc2 * 8,
                         &Al[nb][(i * 256 + tid) * 8]);
            }
#pragma unroll
            for (int i = 0; i < 4; ++i) {
                int row = i * 32 + rowb;
                gl_lds16(Wb + (size_t)(n0 + row) * KP + k0 + sc2 * 8,
                         &Blds[nb][(i * 256 + tid) * 8]);
            }
        }
        bf16x8 af[2][4], bb[2][4];
#pragma unroll
        for (int ks = 0; ks < 2; ++ks)
#pragma unroll
            for (int i = 0; i < 4; ++i) {
                int ch = (ks * 4 + (lane >> 4)) ^ (lane & 7);  // read-side XOR
                int rowA = wm * 64 + i * 16 + (lane & 15);
                af[ks][i] = *reinterpret_cast<const bf16x8*>(&Al[buf][rowA * 64 + ch * 8]);
                int rowB = wn * 64 + i * 16 + (lane & 15);
                bb[ks][i] = *reinterpret_cast<const bf16x8*>(&Blds[buf][rowB * 64 + ch * 8]);
            }
#pragma unroll
        for (int ks = 0; ks < 2; ++ks)
#pragma unroll
            for (int i = 0; i < 4; ++i)
#pragma unroll
                for (int j = 0; j < 4; ++j)
                    acc[i][j] = __builtin_amdgcn_mfma_f32_16x16x32_bf16(
                        af[ks][i], bb[ks][j], acc[i][j], 0, 0, 0);
    }

    // epilogue: D row=(lane>>4)*4+r, col=lane&15
#pragma unroll
    for (int j = 0; j < 4; ++j) {
        int col = n0 + wn * 64 + j * 16 + (lane & 15);
        float bo = bout[col];
#pragma unroll
        for (int i = 0; i < 4; ++i) {
            int rb = m0 + wm * 64 + i * 16 + (lane >> 4) * 4;
            f32x4 v = acc[i][j];
#pragma unroll
            for (int r = 0; r < 4; ++r)
                out[(size_t)(rb + r) * VV + col] = v[r] + bo;
        }
    }
}

// ---------------- fallback GEMM (reads W f32) for small ws -------------------
#define LDSW 40
__global__ __launch_bounds__(256) void gemm_out(const unsigned short* __restrict__ A,
                                                const float* __restrict__ W,
                                                const float* __restrict__ bout,
                                                float* __restrict__ out) {
    __shared__ __align__(16) unsigned short Alds[128 * LDSW];
    __shared__ __align__(16) unsigned short Bl[128 * LDSW];
    int tid = threadIdx.x;
    int lane = tid & 63, wv = tid >> 6;
    int wm = wv >> 1, wn = wv & 1;
    int m0 = blockIdx.y * 128, n0 = blockIdx.x * 128;

    f32x4 acc[4][4];
    f32x4 zero = {0.f, 0.f, 0.f, 0.f};
#pragma unroll
    for (int i = 0; i < 4; ++i)
#pragma unroll
        for (int jj = 0; jj < 4; ++jj) acc[i][jj] = zero;

    for (int k0 = 0; k0 < KP; k0 += 32) {
#pragma unroll
        for (int s = 0; s < 2; ++s) {
            int slot = tid + s * 256;
            int row = slot >> 2, c16 = slot & 3;
            uint4 v = *reinterpret_cast<const uint4*>(
                &A[(size_t)(m0 + row) * KP + k0 + c16 * 8]);
            *reinterpret_cast<uint4*>(&Alds[row * LDSW + c16 * 8]) = v;
        }
#pragma unroll
        for (int s = 0; s < 2; ++s) {
            int slot = tid + s * 256;
            int row = slot >> 2, c8 = slot & 3;
            int k = k0 + c8 * 8;
            __align__(16) unsigned short tmp[8];
            if (k + 7 < H) {
                const float* src = &W[(size_t)(n0 + row) * H + k];
                float4 f0 = *reinterpret_cast<const float4*>(src);
                float4 f1 = *reinterpret_cast<const float4*>(src + 4);
                tmp[0] = f2bf(f0.x); tmp[1] = f2bf(f0.y);
                tmp[2] = f2bf(f0.z); tmp[3] = f2bf(f0.w);
                tmp[4] = f2bf(f1.x); tmp[5] = f2bf(f1.y);
                tmp[6] = f2bf(f1.z); tmp[7] = f2bf(f1.w);
            } else {
#pragma unroll
                for (int jv = 0; jv < 8; ++jv) {
                    int kk = k + jv;
                    tmp[jv] = (kk < H) ? f2bf(W[(size_t)(n0 + row) * H + kk])
                                       : (unsigned short)0;
                }
            }
            *reinterpret_cast<uint4*>(&Bl[row * LDSW + c8 * 8]) =
                *reinterpret_cast<const uint4*>(tmp);
        }
        __syncthreads();
        bf16x8 af[4], bfm[4];
#pragma unroll
        for (int i = 0; i < 4; ++i) {
            int row = wm * 64 + i * 16 + (lane & 15);
            af[i] = *reinterpret_cast<const bf16x8*>(&Alds[row * LDSW + (lane >> 4) * 8]);
        }
#pragma unroll
        for (int i = 0; i < 4; ++i) {
            int row = wn * 64 + i * 16 + (lane & 15);
            bfm[i] = *reinterpret_cast<const bf16x8*>(&Bl[row * LDSW + (lane >> 4) * 8]);
        }
#pragma unroll
        for (int i = 0; i < 4; ++i)
#pragma unroll
            for (int jj = 0; jj < 4; ++jj)
                acc[i][jj] = __builtin_amdgcn_mfma_f32_16x16x32_bf16(
                    af[i], bfm[jj], acc[i][jj], 0, 0, 0);
        __syncthreads();
    }
#pragma unroll
    for (int jj = 0; jj < 4; ++jj) {
        int col = n0 + wn * 64 + jj * 16 + (lane & 15);
        float bo = bout[col];
#pragma unroll
        for (int i = 0; i < 4; ++i) {
            int rb = m0 + wm * 64 + i * 16 + (lane >> 4) * 4;
            f32x4 v = acc[i][jj];
#pragma unroll
            for (int r = 0; r < 4; ++r)
                out[(size_t)(rb + r) * VV + col] = v[r] + bo;
        }
    }
}

// ---------------- host ----------------
extern "C" void kernel_launch(void* const* d_in, const int* in_sizes, int n_in,
                              void* d_out, int out_size, void* d_ws, size_t ws_size,
                              hipStream_t stream) {
    const int*   x       = (const int*)d_in[0];
    const int*   y       = (const int*)d_in[1];
    const float* h0      = (const float*)d_in[2];
    const float* EN      = (const float*)d_in[3];
    const float* ZH      = (const float*)d_in[4];
    const float* enc_Wih = (const float*)d_in[5];
    const float* enc_Whh = (const float*)d_in[6];
    const float* enc_bih = (const float*)d_in[7];
    const float* enc_bhh = (const float*)d_in[8];
    const float* dec_Wih = (const float*)d_in[9];
    const float* dec_Whh = (const float*)d_in[10];
    const float* dec_bih = (const float*)d_in[11];
    const float* dec_bhh = (const float*)d_in[12];
    const float* W_out   = (const float*)d_in[13];
    const float* b_out   = (const float*)d_in[14];
    float* out = (float*)d_out;
    char* base = (char*)d_ws;

    const size_t needA = 23307520, needB = 7742720;
    bool bigws = (ws_size >= needA);
    if (!bigws && ws_size < needB) return;

    float* WT = (float*)base;
    float* P  = (float*)(base + 1440000);
    float *c_, *s2_;
    unsigned short *hdec, *Wb = nullptr;
    if (bigws) {
        Wb   = (unsigned short*)(base + 1440000);
        c_   = (float*)(base + 21920000);
        s2_  = (float*)(base + 21958400);
        hdec = (unsigned short*)(base + 21996800);
    } else {
        c_   = (float*)(base + 6355200);
        s2_  = (float*)(base + 6393600);
        hdec = (unsigned short*)(base + 6432000);
    }

    transpose4<<<dim3(10, 10, 4), dim3(32, 8), 0, stream>>>(
        enc_Wih, enc_Whh, dec_Wih, dec_Whh, WT);
    pproj<<<(BB * S_SRC) / RPB, 192, 0, stream>>>(x, EN, WT, enc_bih, enc_bhh, P);
    encoder3<<<BB, ENC_T, 0, stream>>>(h0, P, enc_Whh, c_);
    sdec<<<BB, 192, 0, stream>>>(c_, WT + 270000, dec_bih, dec_bhh, s2_);
    hdec_k<<<M_ROWS / RPB, 192, 0, stream>>>(y, ZH, WT + 180000, s2_, hdec);
    if (bigws) {
        wcvt<<<(VV * 80) / 256, 256, 0, stream>>>(W_out, Wb);
        gemm2<<<4000, 256, 0, stream>>>(hdec, Wb, b_out, out);
    } else {
        gemm_out<<<dim3(VV / 128, M_ROWS / 128), 256, 0, stream>>>(hdec, W_out, b_out, out);
    }
}

// Round 6
// 256.515 us; speedup vs baseline: 5.9511x; 1.0909x over previous
//
#include <hip/hip_runtime.h>
#include <hip/hip_bf16.h>
#include <stdint.h>

#define BB 32
#define S_SRC 128
#define S_TGT 64
#define H 300
#define VV 32000
#define M_ROWS (BB * S_TGT)   // 2048
#define KP 320                // K padded to multiple of 64

#define MEGA_T 640
#define ENC_BLK 32
#define HDEC_BLK 128          // 16 rows each
#define WCVT_BLK 96

typedef __attribute__((ext_vector_type(8))) __bf16 bf16x8;
typedef __attribute__((ext_vector_type(4))) float f32x4;
typedef __attribute__((ext_vector_type(4))) unsigned short u16x4;
typedef __attribute__((ext_vector_type(2))) __fp16 f16x2;

#if defined(__has_builtin)
#if __has_builtin(__builtin_amdgcn_fdot2)
#define HAVE_FDOT2 1
#endif
#endif

__device__ inline unsigned short f2bf(float f) {
    union { float f; unsigned u; } v; v.f = f;
    unsigned r = (v.u + 0x7FFF + ((v.u >> 16) & 1)) >> 16;  // RNE
    return (unsigned short)r;
}

__device__ __forceinline__ float ftanh(float x) {
    float e = __builtin_amdgcn_exp2f(x * 2.8853900817779268f);
    return 1.0f - 2.0f * __builtin_amdgcn_rcpf(e + 1.0f);
}

__device__ __forceinline__ float fdot2(f16x2 a, f16x2 b, float c) {
#ifdef HAVE_FDOT2
    return __builtin_amdgcn_fdot2(a, b, c, false);
#else
    return c + (float)a.x * (float)b.x + (float)a.y * (float)b.y;
#endif
}

__device__ __forceinline__ void gl_lds16(const void* g, void* l) {
    __builtin_amdgcn_global_load_lds(
        (const __attribute__((address_space(1))) void*)g,
        (__attribute__((address_space(3))) void*)l, 16, 0, 0);
}

// ---------------- transpose the four HxH weight matrices -> ws ----------------
__global__ void transpose4(const float* W0, const float* W1, const float* W2,
                           const float* W3, float* dst) {
    const float* srcs[4] = {W0, W1, W2, W3};
    const float* src = srcs[blockIdx.z];
    float* d = dst + (size_t)blockIdx.z * (H * H);
    __shared__ float tile[32][33];
    int j0 = blockIdx.y * 32, k0 = blockIdx.x * 32;
    for (int r = threadIdx.y; r < 32; r += blockDim.y) {
        int j = j0 + r, k = k0 + threadIdx.x;
        tile[r][threadIdx.x] = (j < H && k < H) ? src[(size_t)j * H + k] : 0.f;
    }
    __syncthreads();
    for (int r = threadIdx.y; r < 32; r += blockDim.y) {
        int k = k0 + r, j = j0 + threadIdx.x;
        if (k < H && j < H) d[(size_t)k * H + j] = tile[threadIdx.x][r];
    }
}

// ---------------- P[m][j] = EN[x[m]] @ WihT + bih + bhh  (m = b*128+t) --------
#define RPB 8
__global__ __launch_bounds__(192) void pproj(const int* __restrict__ x,
                                             const float* __restrict__ EN,
                                             const float* __restrict__ WihT,
                                             const float* __restrict__ bih,
                                             const float* __restrict__ bhh,
                                             float* __restrict__ P) {
    __shared__ float xe[RPB][H];
    int m0 = blockIdx.x * RPB;
    int tid = threadIdx.x;
    for (int r = 0; r < RPB; ++r) {
        int idx = x[m0 + r];
        for (int c = tid; c < H; c += 192) xe[r][c] = EN[(size_t)idx * H + c];
    }
    __syncthreads();
    if (tid < 150) {
        int j = tid * 2;
        float a0[RPB], a1[RPB];
#pragma unroll
        for (int r = 0; r < RPB; ++r) { a0[r] = 0.f; a1[r] = 0.f; }
        const float* wp = WihT + j;
        for (int k = 0; k < H; ++k) {
            float2 w = *reinterpret_cast<const float2*>(wp + (size_t)k * H);
#pragma unroll
            for (int r = 0; r < RPB; ++r) {
                float xv = xe[r][k];
                a0[r] += xv * w.x; a1[r] += xv * w.y;
            }
        }
        float b0 = bih[j] + bhh[j], b1 = bih[j + 1] + bhh[j + 1];
#pragma unroll
        for (int r = 0; r < RPB; ++r) {
            P[(size_t)(m0 + r) * H + j]     = a0[r] + b0;
            P[(size_t)(m0 + r) * H + j + 1] = a1[r] + b1;
        }
    }
}

// ---------------- MEGA kernel: 3 concurrent roles by blockIdx ----------------
// [0,32)         encoder recurrence (1 barrier/step, shfl pair-reduce)
// [32,160)       hdec partial: t1 = ZH[y] @ WihT_d + bih_d   (16 rows/block)
// [160,256)      W_out f32 -> bf16 KP-padded (big-ws only)
__global__ __launch_bounds__(MEGA_T) void mega(
    const float* __restrict__ h0, const float* __restrict__ P,
    const float* __restrict__ Whh, float* __restrict__ c,
    const int* __restrict__ yv, const float* __restrict__ ZH,
    const float* __restrict__ WihT_d, const float* __restrict__ bih_d,
    float* __restrict__ t1,
    const float* __restrict__ W, unsigned short* __restrict__ Wb) {
    __shared__ union {
        __fp16 hb[2][304];      // encoder h double-buffer (f16)
        float  ye[16][304];     // hdec embedding tile
    } L;
    int blk = blockIdx.x, tid = threadIdx.x;

    if (blk < ENC_BLK) {
        // ================= encoder =================
        int b = blk;
        bool act = tid < 600;
        int j = tid >> 1, half = tid & 1;   // row j, k-half
        f16x2 w[76];
        if (act) {
            const float* wr = Whh + (size_t)j * H + half * 150;
#pragma unroll
            for (int i = 0; i < 75; ++i) {
                float2 f = *reinterpret_cast<const float2*>(wr + 2 * i);
                w[i] = __builtin_amdgcn_cvt_pkrtz(f.x, f.y);
            }
            w[75] = __builtin_amdgcn_cvt_pkrtz(0.f, 0.f);
        }
        // init h buffer 0 + zero the 4 pad slots of both buffers
        if (act && half == 0) {
            int pos = j < 150 ? j : j + 2;
            L.hb[0][pos] = (__fp16)h0[(size_t)b * H + j];
        }
        if (tid >= 600 && tid < 608) {
            int pi = tid - 600, bufi = pi >> 2, q = pi & 3;
            int idx = (q < 2) ? (150 + q) : (302 + (q - 2));
            L.hb[bufi][idx] = (__fp16)0.f;
        }
        __syncthreads();

        const float* Pb = P + (size_t)b * S_SRC * H;
        int cur = 0;
        for (int t = 0; t < S_SRC; ++t) {
            float pv = 0.f;
            if (act && half == 0) pv = Pb[(size_t)t * H + j];   // hides under dots
            float tot = 0.f;
            if (act) {
                float a0 = 0.f, a1 = 0.f, a2 = 0.f, a3 = 0.f;
                const uint2* hp =
                    reinterpret_cast<const uint2*>(&L.hb[cur][half * 152]);
#pragma unroll
                for (int i = 0; i < 38; i += 2) {
                    uint2 qa = hp[i];
                    uint2 qb = hp[i + 1];
                    a0 = fdot2(w[2 * i],     __builtin_bit_cast(f16x2, qa.x), a0);
                    a1 = fdot2(w[2 * i + 1], __builtin_bit_cast(f16x2, qa.y), a1);
                    a2 = fdot2(w[2 * i + 2], __builtin_bit_cast(f16x2, qb.x), a2);
                    a3 = fdot2(w[2 * i + 3], __builtin_bit_cast(f16x2, qb.y), a3);
                }
                float a = (a0 + a1) + (a2 + a3);
                tot = a + __shfl_xor(a, 1, 64);   // pair (2j,2j+1) same wave
                if (half == 0) {
                    float hv = ftanh(tot + pv);
                    int pos = j < 150 ? j : j + 2;
                    L.hb[cur ^ 1][pos] = (__fp16)hv;
                }
            }
            __syncthreads();
            cur ^= 1;
        }
        if (act && half == 0) {
            int pos = j < 150 ? j : j + 2;
            c[(size_t)b * H + j] = (float)L.hb[cur][pos];
        }
    } else if (blk < ENC_BLK + HDEC_BLK) {
        // ================= hdec partial GEMM =================
        int bi = blk - ENC_BLK;
        int m0 = bi * 16;
        for (int i = tid; i < 16 * 304; i += MEGA_T) {
            int r = i / 304, cc = i - r * 304;
            L.ye[r][cc] = (cc < H) ? ZH[(size_t)yv[m0 + r] * H + cc] : 0.f;
        }
        __syncthreads();
        if (tid < 600) {
            int rg = tid / 150, jp = tid - rg * 150, j0 = 2 * jp;
            float a[4][2] = {};
            const float* wp = WihT_d + j0;
            for (int k = 0; k < H; k += 2) {
                float2 wa = *reinterpret_cast<const float2*>(wp + (size_t)k * H);
                float2 wb = *reinterpret_cast<const float2*>(wp + (size_t)(k + 1) * H);
#pragma unroll
                for (int r = 0; r < 4; ++r) {
                    float2 x = *reinterpret_cast<const float2*>(&L.ye[rg * 4 + r][k]);
                    a[r][0] += x.x * wa.x + x.y * wb.x;
                    a[r][1] += x.x * wa.y + x.y * wb.y;
                }
            }
            float b0 = bih_d[j0], b1 = bih_d[j0 + 1];
#pragma unroll
            for (int r = 0; r < 4; ++r) {
                *reinterpret_cast<float2*>(&t1[(size_t)(m0 + rg * 4 + r) * 304 + j0]) =
                    make_float2(a[r][0] + b0, a[r][1] + b1);
            }
        }
    } else if (Wb != nullptr) {
        // ================= wcvt =================
        for (int id = (blk - (ENC_BLK + HDEC_BLK)) * MEGA_T + tid; id < VV * 80;
             id += WCVT_BLK * MEGA_T) {
            int row = id / 80, cq = id - row * 80;
            int k = cq * 4;
            u16x4 o;
            if (k < H) {
                float4 f = *reinterpret_cast<const float4*>(W + (size_t)row * H + k);
                o[0] = f2bf(f.x); o[1] = f2bf(f.y); o[2] = f2bf(f.z); o[3] = f2bf(f.w);
            } else {
                o[0] = 0; o[1] = 0; o[2] = 0; o[3] = 0;
            }
            *reinterpret_cast<u16x4*>(Wb + (size_t)row * KP + k) = o;
        }
    }
}

// ---------------- s2[b][j] = c[b] @ WhhT_d + bhh_d ---------------------------
__global__ __launch_bounds__(192) void sdec(const float* __restrict__ c,
                                            const float* __restrict__ WhhT_d,
                                            const float* __restrict__ bhh_d,
                                            float* __restrict__ s2) {
    __shared__ float cl[H];
    int b = blockIdx.x, tid = threadIdx.x;
    for (int k = tid; k < H; k += 192) cl[k] = c[(size_t)b * H + k];
    __syncthreads();
    if (tid < 150) {
        int j = tid * 2;
        float a0 = 0.f, a1 = 0.f;
        const float* wp = WhhT_d + j;
        for (int k = 0; k < H; ++k) {
            float2 w = *reinterpret_cast<const float2*>(wp + (size_t)k * H);
            a0 += cl[k] * w.x; a1 += cl[k] * w.y;
        }
        s2[(size_t)b * H + j]     = a0 + bhh_d[j];
        s2[(size_t)b * H + j + 1] = a1 + bhh_d[j + 1];
    }
}

// ---------------- hdec[m][j] = bf16(tanh(t1[m][j] + s2[b][j])), pad to 320 ---
__global__ __launch_bounds__(256) void hdec_fin(const float* __restrict__ t1,
                                                const float* __restrict__ s2,
                                                unsigned short* __restrict__ hdec) {
    int blk = blockIdx.x, tid = threadIdx.x;   // 256 blocks x 8 rows
    for (int i = tid; i < 8 * KP; i += 256) {
        int r = i / KP, j = i - r * KP;
        int m = blk * 8 + r, b = m >> 6;
        unsigned short v = 0;
        if (j < H)
            v = f2bf(ftanh(t1[(size_t)m * 304 + j] + s2[(size_t)b * H + j]));
        hdec[(size_t)m * KP + j] = v;
    }
}

// ---------------- out = hdec[2048,320] @ Wb[32000,320]^T + b_out -------------
__global__ __launch_bounds__(256) void gemm2(const unsigned short* __restrict__ A,
                                             const unsigned short* __restrict__ Wb,
                                             const float* __restrict__ bout,
                                             float* __restrict__ out) {
    __shared__ unsigned short Al[2][128 * 64];
    __shared__ unsigned short Blds[2][128 * 64];
    int tid = threadIdx.x;
    int lane = tid & 63, wv = tid >> 6;
    int wm = wv >> 1, wn = wv & 1;           // 2x2 waves, 64x64 each

    int orig = blockIdx.x;                    // 4000 blocks
    int wg = (orig & 7) * 500 + (orig >> 3);  // bijective XCD swizzle (4000%8==0)
    int mi = wg & 15, ni = wg >> 4;           // m-fastest
    int m0 = mi * 128, n0 = ni * 128;

    int rowb = tid >> 3;
    int sc2 = (tid & 7) ^ (rowb & 7);         // pre-swizzled source chunk

    f32x4 acc[4][4];
    f32x4 zero = {0.f, 0.f, 0.f, 0.f};
#pragma unroll
    for (int i = 0; i < 4; ++i)
#pragma unroll
        for (int j = 0; j < 4; ++j) acc[i][j] = zero;

#pragma unroll
    for (int i = 0; i < 4; ++i) {
        int row = i * 32 + rowb;
        gl_lds16(A + (size_t)(m0 + row) * KP + sc2 * 8, &Al[0][(i * 256 + tid) * 8]);
    }
#pragma unroll
    for (int i = 0; i < 4; ++i) {
        int row = i * 32 + rowb;
        gl_lds16(Wb + (size_t)(n0 + row) * KP + sc2 * 8, &Blds[0][(i * 256 + tid) * 8]);
    }

    for (int t = 0; t < 5; ++t) {
        __syncthreads();
        int buf = t & 1;
        if (t < 4) {   // prefetch first: max latency cover before next barrier
            int k0 = (t + 1) * 64, nb = buf ^ 1;
#pragma unroll
            for (int i = 0; i < 4; ++i) {
                int row = i * 32 + rowb;
                gl_lds16(A + (size_t)(m0 + row) * KP + k0 + sc2 * 8,
                         &Al[nb][(i * 256 + tid) * 8]);
            }
#pragma unroll
            for (int i = 0; i < 4; ++i) {
                int row = i * 32 + rowb;
                gl_lds16(Wb + (size_t)(n0 + row) * KP + k0 + sc2 * 8,
                         &Blds[nb][(i * 256 + tid) * 8]);
            }
        }
        bf16x8 af[2][4], bb[2][4];
#pragma unroll
        for (int ks = 0; ks < 2; ++ks)
#pragma unroll
            for (int i = 0; i < 4; ++i) {
                int ch = (ks * 4 + (lane >> 4)) ^ (lane & 7);  // read-side XOR
                int rowA = wm * 64 + i * 16 + (lane & 15);
                af[ks][i] = *reinterpret_cast<const bf16x8*>(&Al[buf][rowA * 64 + ch * 8]);
                int rowB = wn * 64 + i * 16 + (lane & 15);
                bb[ks][i] = *reinterpret_cast<const bf16x8*>(&Blds[buf][rowB * 64 + ch * 8]);
            }
#pragma unroll
        for (int ks = 0; ks < 2; ++ks)
#pragma unroll
            for (int i = 0; i < 4; ++i)
#pragma unroll
                for (int j = 0; j < 4; ++j)
                    acc[i][j] = __builtin_amdgcn_mfma_f32_16x16x32_bf16(
                        af[ks][i], bb[ks][j], acc[i][j], 0, 0, 0);
    }

#pragma unroll
    for (int j = 0; j < 4; ++j) {
        int col = n0 + wn * 64 + j * 16 + (lane & 15);
        float bo = bout[col];
#pragma unroll
        for (int i = 0; i < 4; ++i) {
            int rb = m0 + wm * 64 + i * 16 + (lane >> 4) * 4;
            f32x4 v = acc[i][j];
#pragma unroll
            for (int r = 0; r < 4; ++r)
                out[(size_t)(rb + r) * VV + col] = v[r] + bo;
        }
    }
}

// ---------------- fallback GEMM (reads W f32) for small ws -------------------
#define LDSW 40
__global__ __launch_bounds__(256) void gemm_out(const unsigned short* __restrict__ A,
                                                const float* __restrict__ W,
                                                const float* __restrict__ bout,
                                                float* __restrict__ out) {
    __shared__ __align__(16) unsigned short Alds[128 * LDSW];
    __shared__ __align__(16) unsigned short Bl[128 * LDSW];
    int tid = threadIdx.x;
    int lane = tid & 63, wv = tid >> 6;
    int wm = wv >> 1, wn = wv & 1;
    int m0 = blockIdx.y * 128, n0 = blockIdx.x * 128;

    f32x4 acc[4][4];
    f32x4 zero = {0.f, 0.f, 0.f, 0.f};
#pragma unroll
    for (int i = 0; i < 4; ++i)
#pragma unroll
        for (int jj = 0; jj < 4; ++jj) acc[i][jj] = zero;

    for (int k0 = 0; k0 < KP; k0 += 32) {
#pragma unroll
        for (int s = 0; s < 2; ++s) {
            int slot = tid + s * 256;
            int row = slot >> 2, c16 = slot & 3;
            uint4 v = *reinterpret_cast<const uint4*>(
                &A[(size_t)(m0 + row) * KP + k0 + c16 * 8]);
            *reinterpret_cast<uint4*>(&Alds[row * LDSW + c16 * 8]) = v;
        }
#pragma unroll
        for (int s = 0; s < 2; ++s) {
            int slot = tid + s * 256;
            int row = slot >> 2, c8 = slot & 3;
            int k = k0 + c8 * 8;
            __align__(16) unsigned short tmp[8];
            if (k + 7 < H) {
                const float* src = &W[(size_t)(n0 + row) * H + k];
                float4 f0 = *reinterpret_cast<const float4*>(src);
                float4 f1 = *reinterpret_cast<const float4*>(src + 4);
                tmp[0] = f2bf(f0.x); tmp[1] = f2bf(f0.y);
                tmp[2] = f2bf(f0.z); tmp[3] = f2bf(f0.w);
                tmp[4] = f2bf(f1.x); tmp[5] = f2bf(f1.y);
                tmp[6] = f2bf(f1.z); tmp[7] = f2bf(f1.w);
            } else {
#pragma unroll
                for (int jv = 0; jv < 8; ++jv) {
                    int kk = k + jv;
                    tmp[jv] = (kk < H) ? f2bf(W[(size_t)(n0 + row) * H + kk])
                                       : (unsigned short)0;
                }
            }
            *reinterpret_cast<uint4*>(&Bl[row * LDSW + c8 * 8]) =
                *reinterpret_cast<const uint4*>(tmp);
        }
        __syncthreads();
        bf16x8 af[4], bfm[4];
#pragma unroll
        for (int i = 0; i < 4; ++i) {
            int row = wm * 64 + i * 16 + (lane & 15);
            af[i] = *reinterpret_cast<const bf16x8*>(&Alds[row * LDSW + (lane >> 4) * 8]);
        }
#pragma unroll
        for (int i = 0; i < 4; ++i) {
            int row = wn * 64 + i * 16 + (lane & 15);
            bfm[i] = *reinterpret_cast<const bf16x8*>(&Bl[row * LDSW + (lane >> 4) * 8]);
        }
#pragma unroll
        for (int i = 0; i < 4; ++i)
#pragma unroll
            for (int jj = 0; jj < 4; ++jj)
                acc[i][jj] = __builtin_amdgcn_mfma_f32_16x16x32_bf16(
                    af[i], bfm[jj], acc[i][jj], 0, 0, 0);
        __syncthreads();
    }
#pragma unroll
    for (int jj = 0; jj < 4; ++jj) {
        int col = n0 + wn * 64 + jj * 16 + (lane & 15);
        float bo = bout[col];
#pragma unroll
        for (int i = 0; i < 4; ++i) {
            int rb = m0 + wm * 64 + i * 16 + (lane >> 4) * 4;
            f32x4 v = acc[i][jj];
#pragma unroll
            for (int r = 0; r < 4; ++r)
                out[(size_t)(rb + r) * VV + col] = v[r] + bo;
        }
    }
}

// ---------------- host ----------------
extern "C" void kernel_launch(void* const* d_in, const int* in_sizes, int n_in,
                              void* d_out, int out_size, void* d_ws, size_t ws_size,
                              hipStream_t stream) {
    const int*   x       = (const int*)d_in[0];
    const int*   y       = (const int*)d_in[1];
    const float* h0      = (const float*)d_in[2];
    const float* EN      = (const float*)d_in[3];
    const float* ZH      = (const float*)d_in[4];
    const float* enc_Wih = (const float*)d_in[5];
    const float* enc_Whh = (const float*)d_in[6];
    const float* enc_bih = (const float*)d_in[7];
    const float* enc_bhh = (const float*)d_in[8];
    const float* dec_Wih = (const float*)d_in[9];
    const float* dec_Whh = (const float*)d_in[10];
    const float* dec_bih = (const float*)d_in[11];
    const float* dec_bhh = (const float*)d_in[12];
    const float* W_out   = (const float*)d_in[13];
    const float* b_out   = (const float*)d_in[14];
    float* out = (float*)d_out;
    char* base = (char*)d_ws;

    // ws layout (bytes):
    //   0          WT (4x HxH transposed f32, 1,440,000)
    //   big path:  1,440,000 Wb bf16 [32000x320] (20,480,000)
    //              21,920,000 c ; 21,958,400 s2 ; 21,996,800 hdec [2048x320 u16]
    //   small:     1,440,000 c ; 1,478,400 s2 ; 1,516,800 hdec
    // P (4.9 MB) and t1 (2.5 MB) live in d_out as scratch: both are fully
    // consumed (encoder / hdec_fin) before gemm2 overwrites all of d_out.
    const size_t needA = 23307520, needB = 2827520;
    bool bigws = (ws_size >= needA);
    if (!bigws && ws_size < needB) return;

    float* WT = (float*)base;
    float *c_, *s2_;
    unsigned short *hdec, *Wb = nullptr;
    if (bigws) {
        Wb   = (unsigned short*)(base + 1440000);
        c_   = (float*)(base + 21920000);
        s2_  = (float*)(base + 21958400);
        hdec = (unsigned short*)(base + 21996800);
    } else {
        c_   = (float*)(base + 1440000);
        s2_  = (float*)(base + 1478400);
        hdec = (unsigned short*)(base + 1516800);
    }
    float* P  = out;                 // [4096x300] f32 = 4,915,200 B
    float* t1 = out + 2000000;       // [2048x304] f32 = 2,490,368 B (disjoint)

    transpose4<<<dim3(10, 10, 4), dim3(32, 8), 0, stream>>>(
        enc_Wih, enc_Whh, dec_Wih, dec_Whh, WT);
    pproj<<<(BB * S_SRC) / RPB, 192, 0, stream>>>(x, EN, WT, enc_bih, enc_bhh, P);
    int mega_grid = bigws ? (ENC_BLK + HDEC_BLK + WCVT_BLK) : (ENC_BLK + HDEC_BLK);
    mega<<<mega_grid, MEGA_T, 0, stream>>>(h0, P, enc_Whh, c_, y, ZH,
                                           WT + 180000, dec_bih, t1, W_out, Wb);
    sdec<<<BB, 192, 0, stream>>>(c_, WT + 270000, dec_bhh, s2_);
    hdec_fin<<<M_ROWS / 8, 256, 0, stream>>>(t1, s2_, hdec);
    if (bigws) {
        gemm2<<<4000, 256, 0, stream>>>(hdec, Wb, b_out, out);
    } else {
        gemm_out<<<dim3(VV / 128, M_ROWS / 128), 256, 0, stream>>>(hdec, W_out, b_out, out);
    }
}